// Round 1
// baseline (1263.586 us; speedup 1.0000x reference)
//
#include <hip/hip_runtime.h>
#include <math.h>

// HAN (2-layer) on MI355X. f32 throughout (correctness-first baseline).
// Layer-2 computes only what the author output needs (edge types 1,3).

#define NA 20000
#define NP 30000
#define NE 200000
#define D1 256   // HID
#define D2 128   // OUT

static __device__ __forceinline__ float lrelu(float x) { return x >= 0.f ? x : 0.2f * x; }

// ---------------- CSR build ----------------
__global__ void count_deg(const int* __restrict__ dstv, int* __restrict__ cnt, int n) {
    int i = blockIdx.x * blockDim.x + threadIdx.x;
    if (i < n) atomicAdd(&cnt[dstv[i]], 1);
}

__global__ void fill_csr(const int* __restrict__ dstv, int* __restrict__ cursor,
                         int* __restrict__ eidv, int n) {
    int i = blockIdx.x * blockDim.x + threadIdx.x;
    if (i < n) { int p = atomicAdd(&cursor[dstv[i]], 1); eidv[p] = i; }
}

// single-block exclusive scan (n ~ 30000); writes rowptr[0..n] and cursor copy.
// in may alias cursor (each element read once by its own thread before write).
__global__ __launch_bounds__(1024) void exscan(const int* __restrict__ in,
                                               int* __restrict__ rowptr,
                                               int* __restrict__ cursor, int n) {
    __shared__ int buf[2][1024];
    __shared__ int carry_s;
    const int t = threadIdx.x;
    if (t == 0) carry_s = 0;
    __syncthreads();
    for (int base = 0; base < n; base += 1024) {
        int i = base + t;
        int v = (i < n) ? in[i] : 0;
        int cur = 0;
        buf[0][t] = v;
        __syncthreads();
        for (int off = 1; off < 1024; off <<= 1) {
            int add = (t >= off) ? buf[cur][t - off] : 0;
            buf[cur ^ 1][t] = buf[cur][t] + add;
            cur ^= 1;
            __syncthreads();
        }
        int incl = buf[cur][t];
        int carry = carry_s;
        if (i < n) { int ex = carry + incl - v; rowptr[i] = ex; cursor[i] = ex; }
        __syncthreads();
        if (t == 1023) carry_s = carry + incl;
        __syncthreads();
    }
    if (t == 0) rowptr[n] = carry_s;
}

// ---------------- GEMM (f32, 64x64 tile, 4x4 microtile) ----------------
// SCORE=false: C = A@W + bias              (store)
// SCORE=true : atomicAdd(score_out, sum_n sum_f tanh((A@W)[n,f]+bias[f])*q[f])
template <bool SCORE>
__global__ __launch_bounds__(256) void gemm64(
    const float* __restrict__ A, const float* __restrict__ W,
    const float* __restrict__ bias, float* __restrict__ C,
    const float* __restrict__ qv, float* __restrict__ score_out,
    int M, int K, int N) {
    __shared__ float As[16][68];
    __shared__ float Bs[16][64];
    __shared__ float red[256];
    const int t = threadIdx.x;
    const int tx = t & 15, ty = t >> 4;
    const int bm = blockIdx.x * 64, bn = blockIdx.y * 64;
    const int ka = t & 15, ma = t >> 4;
    const int cb = t & 63, kb0 = t >> 6;
    float c[4][4] = {};
    for (int kt = 0; kt < K; kt += 16) {
#pragma unroll
        for (int i = 0; i < 4; ++i) {
            int m = ma + 16 * i;
            int gr = bm + m;
            As[ka][m] = (gr < M) ? A[(size_t)gr * K + kt + ka] : 0.f;
        }
#pragma unroll
        for (int i = 0; i < 4; ++i) {
            int k = kb0 + 4 * i;
            Bs[k][cb] = W[(size_t)(kt + k) * N + bn + cb];
        }
        __syncthreads();
#pragma unroll
        for (int k = 0; k < 16; ++k) {
            float4 av = *(const float4*)&As[k][ty * 4];
            float4 bv = *(const float4*)&Bs[k][tx * 4];
            float aa[4] = {av.x, av.y, av.z, av.w};
            float bb[4] = {bv.x, bv.y, bv.z, bv.w};
#pragma unroll
            for (int i = 0; i < 4; ++i)
#pragma unroll
                for (int j = 0; j < 4; ++j) c[i][j] = fmaf(aa[i], bb[j], c[i][j]);
        }
        __syncthreads();
    }
    if constexpr (!SCORE) {
        const float4 bi = *(const float4*)&bias[bn + tx * 4];
#pragma unroll
        for (int i = 0; i < 4; ++i) {
            int gr = bm + ty * 4 + i;
            if (gr >= M) continue;
            float4 o = {c[i][0] + bi.x, c[i][1] + bi.y, c[i][2] + bi.z, c[i][3] + bi.w};
            *(float4*)&C[(size_t)gr * N + bn + tx * 4] = o;
        }
    } else {
        const float4 bi = *(const float4*)&bias[bn + tx * 4];
        const float4 qq = *(const float4*)&qv[bn + tx * 4];
        const float bb2[4] = {bi.x, bi.y, bi.z, bi.w};
        const float qq2[4] = {qq.x, qq.y, qq.z, qq.w};
        float partial = 0.f;
#pragma unroll
        for (int i = 0; i < 4; ++i) {
            int gr = bm + ty * 4 + i;
            if (gr >= M) continue;
#pragma unroll
            for (int j = 0; j < 4; ++j) partial += tanhf(c[i][j] + bb2[j]) * qq2[j];
        }
        red[t] = partial;
        __syncthreads();
        for (int s = 128; s > 0; s >>= 1) {
            if (t < s) red[t] += red[t + s];
            __syncthreads();
        }
        if (t == 0) atomicAdd(score_out, red[0]);
    }
}

// ---------------- per-node attention scalars: s[n,h] = <h[n,h,:], att[h,:]> ----------------
template <int HD>
__global__ __launch_bounds__(256) void node_scores(const float* __restrict__ h,
                                                   const float* __restrict__ att,
                                                   float* __restrict__ s, int n) {
    const int idx = blockIdx.x * blockDim.x + threadIdx.x;
    const int node = idx >> 2, hh = idx & 3;
    if (node >= n) return;
    const float* row = h + (size_t)node * (4 * HD) + hh * HD;
    const float* ar = att + hh * HD;
    float acc = 0.f;
#pragma unroll
    for (int d = 0; d < HD; d += 4) {
        float4 x = *(const float4*)&row[d];
        float4 a = *(const float4*)&ar[d];
        acc = fmaf(x.x, a.x, acc); acc = fmaf(x.y, a.y, acc);
        acc = fmaf(x.z, a.z, acc); acc = fmaf(x.w, a.w, acc);
    }
    s[idx] = acc;
}

// ---------------- fused segment softmax + weighted aggregation + relu ----------------
// one wave per dst node; CSR gather; out[n] = relu(sum_e xs[src]*exp(a-amax) / (denom+1e-16))
template <int D>
__global__ __launch_bounds__(256) void agg_norm(
    const float* __restrict__ xs, const float* __restrict__ ssrc,
    const float* __restrict__ sdst, const int* __restrict__ srcIdx,
    const int* __restrict__ rowptr, const int* __restrict__ eidv,
    float* __restrict__ out, int n_dst) {
    constexpr int VPL = D / 64;
    const int wid = (int)((blockIdx.x * (size_t)blockDim.x + threadIdx.x) >> 6);
    const int lane = threadIdx.x & 63;
    if (wid >= n_dst) return;
    const int e0 = rowptr[wid], e1 = rowptr[wid + 1];
    const int h = lane >> 4;
    const float4 sdv = *(const float4*)&sdst[wid * 4];
    const float sdh[4] = {sdv.x, sdv.y, sdv.z, sdv.w};
    // pass 1: per-head max over incoming edges (edges distributed over lanes)
    float mx[4] = {-INFINITY, -INFINITY, -INFINITY, -INFINITY};
    for (int e = e0 + lane; e < e1; e += 64) {
        const int r = srcIdx[eidv[e]];
        const float4 ssv = *(const float4*)&ssrc[r * 4];
        const float ss4[4] = {ssv.x, ssv.y, ssv.z, ssv.w};
#pragma unroll
        for (int k = 0; k < 4; ++k) mx[k] = fmaxf(mx[k], lrelu(ss4[k] + sdh[k]));
    }
#pragma unroll
    for (int k = 0; k < 4; ++k) {
#pragma unroll
        for (int off = 32; off > 0; off >>= 1) mx[k] = fmaxf(mx[k], __shfl_xor(mx[k], off));
    }
    const float myMax = mx[h], mySd = sdh[h];
    // pass 2: accumulate exp-weighted features + denom (lane owns D/64 elems of one head)
    float acc[VPL] = {};
    float denom = 0.f;
    for (int e = e0; e < e1; ++e) {
        const int r = srcIdx[eidv[e]];
        const float a = lrelu(ssrc[r * 4 + h] + mySd);
        const float ea = expf(a - myMax);
        denom += ea;
        const float* xr = xs + (size_t)r * D + lane * VPL;
        if constexpr (VPL == 4) {
            float4 x = *(const float4*)xr;
            acc[0] += x.x * ea; acc[1] += x.y * ea; acc[2] += x.z * ea; acc[3] += x.w * ea;
        } else {
            float2 x = *(const float2*)xr;
            acc[0] += x.x * ea; acc[1] += x.y * ea;
        }
    }
    const float inv = 1.f / (denom + 1e-16f);
    float* orow = out + (size_t)wid * D + lane * VPL;
    if constexpr (VPL == 4) {
        float4 o = {fmaxf(acc[0] * inv, 0.f), fmaxf(acc[1] * inv, 0.f),
                    fmaxf(acc[2] * inv, 0.f), fmaxf(acc[3] * inv, 0.f)};
        *(float4*)orow = o;
    } else {
        float2 o = {fmaxf(acc[0] * inv, 0.f), fmaxf(acc[1] * inv, 0.f)};
        *(float2*)orow = o;
    }
}

// ---------------- semantic softmax (M=2) + combine ----------------
__global__ void softmax2(const float* __restrict__ score, float invN, float* __restrict__ attn) {
    const float s0 = score[0] * invN, s1 = score[1] * invN;
    const float m = fmaxf(s0, s1);
    const float e0 = expf(s0 - m), e1 = expf(s1 - m);
    const float d = e0 + e1;
    attn[0] = e0 / d;
    attn[1] = e1 / d;
}

__global__ __launch_bounds__(256) void combine2(const float* __restrict__ a,
                                                const float* __restrict__ b,
                                                const float* __restrict__ attn,
                                                float* __restrict__ out, int n4) {
    const int i = blockIdx.x * blockDim.x + threadIdx.x;
    if (i >= n4) return;
    const float w0 = attn[0], w1 = attn[1];
    float4 x = ((const float4*)a)[i], y = ((const float4*)b)[i];
    float4 o = {w0 * x.x + w1 * y.x, w0 * x.y + w1 * y.y,
                w0 * x.z + w1 * y.z, w0 * x.w + w1 * y.w};
    ((float4*)out)[i] = o;
}

static inline int cdiv(int a, int b) { return (a + b - 1) / b; }

extern "C" void kernel_launch(void* const* d_in, const int* in_sizes, int n_in,
                              void* d_out, int out_size, void* d_ws, size_t ws_size,
                              hipStream_t stream) {
    const float* x_a = (const float*)d_in[0];
    const float* x_p = (const float*)d_in[1];
    const int* src[4] = {(const int*)d_in[2], (const int*)d_in[4], (const int*)d_in[6], (const int*)d_in[8]};
    const int* dst[4] = {(const int*)d_in[3], (const int*)d_in[5], (const int*)d_in[7], (const int*)d_in[9]};
    const float* W1a = (const float*)d_in[10]; const float* b1a = (const float*)d_in[11];
    const float* W1p = (const float*)d_in[12]; const float* b1p = (const float*)d_in[13];
    const float* att1s = (const float*)d_in[14]; const float* att1d = (const float*)d_in[15];
    const float* q1 = (const float*)d_in[16];
    const float* k1W = (const float*)d_in[17]; const float* k1b = (const float*)d_in[18];
    const float* W2a = (const float*)d_in[19]; const float* b2a = (const float*)d_in[20];
    const float* W2p = (const float*)d_in[21]; const float* b2p = (const float*)d_in[22];
    const float* att2s = (const float*)d_in[23]; const float* att2d = (const float*)d_in[24];
    const float* q2 = (const float*)d_in[25];
    const float* k2W = (const float*)d_in[26]; const float* k2b = (const float*)d_in[27];

    // ---- workspace layout (floats), with lifetime-based reuse ----
    float* ws = (float*)d_ws;
    float* h1a = ws;                                  // [NA,256]
    float* h1p = h1a + (size_t)NA * D1;               // [NP,256]
    float* agg0 = h1p + (size_t)NP * D1;              // [NP,256] a->p
    float* agg1 = agg0 + (size_t)NP * D1;             // [NA,256] p->a
    float* agg2 = agg1 + (size_t)NA * D1;             // [NP,256] p->p
    float* agg3 = agg2 + (size_t)NP * D1;             // [NA,256] a->a
    float* sv = agg3 + (size_t)NA * D1;               // per-type per-node attention scalars
    float* ss0 = sv;            float* sd0 = ss0 + NA * 4;
    float* ss1 = sd0 + NP * 4;  float* sd1 = ss1 + NP * 4;
    float* ss2 = sd1 + NA * 4;  float* sd2 = ss2 + NP * 4;
    float* ss3 = sd2 + NP * 4;  float* sd3 = ss3 + NA * 4;
    float* sc = sd3 + NA * 4;   // 16 floats: [0..1]=score_p, [2..3]=score_a, [4..5]=score2_a, [6..7]=attn_p, [8..9]=attn_a, [10..11]=attn2
    int* csr = (int*)(sc + 16);
    const int nd[4] = {NP, NA, NP, NA};
    int* rp[4]; int* cur[4]; int* eid[4];
    int* p = csr;
    for (int i = 0; i < 4; ++i) { rp[i] = p; p += nd[i] + 1; }
    int* cur0 = p;
    for (int i = 0; i < 4; ++i) { cur[i] = p; p += nd[i]; }
    for (int i = 0; i < 4; ++i) { eid[i] = p; p += NE; }
    const size_t need_bytes = (size_t)((char*)p - (char*)d_ws);
    if (ws_size < need_bytes) return;  // loud failure (output stays zero) rather than corruption

    // region reuse after layer-1 aggregation:
    float* res_a = h1a;   // [NA,256]
    float* res_p = h1p;   // [NP,256]
    float* h2a = agg0;    // [NA,128]
    float* h2p = agg2;    // [NP,128]
    float* g21 = agg1;    // [NA,128] layer2 p->a
    float* g23 = agg3;    // [NA,128] layer2 a->a
    float* ss21 = sv;            float* sd21 = ss21 + NP * 4;
    float* ss23 = sd21 + NA * 4; float* sd23 = ss23 + NA * 4;

    // ---- 0. zero accumulators ----
    hipMemsetAsync(cur0, 0, (size_t)(NP + NA + NP + NA) * sizeof(int), stream);
    hipMemsetAsync(sc, 0, 16 * sizeof(float), stream);

    // ---- 1. CSR build (edge sets shared by both layers) ----
    for (int i = 0; i < 4; ++i)
        count_deg<<<cdiv(NE, 256), 256, 0, stream>>>(dst[i], cur[i], NE);
    for (int i = 0; i < 4; ++i)
        exscan<<<1, 1024, 0, stream>>>(cur[i], rp[i], cur[i], nd[i]);
    for (int i = 0; i < 4; ++i)
        fill_csr<<<cdiv(NE, 256), 256, 0, stream>>>(dst[i], cur[i], eid[i], NE);

    // ---- 2. layer-1 transforms ----
    gemm64<false><<<dim3(cdiv(NA, 64), 4), 256, 0, stream>>>(x_a, W1a, b1a, h1a, nullptr, nullptr, NA, 256, 256);
    gemm64<false><<<dim3(cdiv(NP, 64), 4), 256, 0, stream>>>(x_p, W1p, b1p, h1p, nullptr, nullptr, NP, 256, 256);

    // ---- 3. per-node attention scalars (layer 1); att1_*[i] is 256 floats ----
    node_scores<64><<<cdiv(NA * 4, 256), 256, 0, stream>>>(h1a, att1s + 0 * 256, ss0, NA);
    node_scores<64><<<cdiv(NP * 4, 256), 256, 0, stream>>>(h1p, att1d + 0 * 256, sd0, NP);
    node_scores<64><<<cdiv(NP * 4, 256), 256, 0, stream>>>(h1p, att1s + 1 * 256, ss1, NP);
    node_scores<64><<<cdiv(NA * 4, 256), 256, 0, stream>>>(h1a, att1d + 1 * 256, sd1, NA);
    node_scores<64><<<cdiv(NP * 4, 256), 256, 0, stream>>>(h1p, att1s + 2 * 256, ss2, NP);
    node_scores<64><<<cdiv(NP * 4, 256), 256, 0, stream>>>(h1p, att1d + 2 * 256, sd2, NP);
    node_scores<64><<<cdiv(NA * 4, 256), 256, 0, stream>>>(h1a, att1s + 3 * 256, ss3, NA);
    node_scores<64><<<cdiv(NA * 4, 256), 256, 0, stream>>>(h1a, att1d + 3 * 256, sd3, NA);

    // ---- 4. layer-1 fused segment-softmax aggregation ----
    agg_norm<256><<<cdiv(NP, 4), 256, 0, stream>>>(h1a, ss0, sd0, src[0], rp[0], eid[0], agg0, NP);
    agg_norm<256><<<cdiv(NA, 4), 256, 0, stream>>>(h1p, ss1, sd1, src[1], rp[1], eid[1], agg1, NA);
    agg_norm<256><<<cdiv(NP, 4), 256, 0, stream>>>(h1p, ss2, sd2, src[2], rp[2], eid[2], agg2, NP);
    agg_norm<256><<<cdiv(NA, 4), 256, 0, stream>>>(h1a, ss3, sd3, src[3], rp[3], eid[3], agg3, NA);

    // ---- 5. semantic scores (layer 1): q . mean_n tanh(stk@kW+kb) ----
    gemm64<true><<<dim3(cdiv(NP, 64), 4), 256, 0, stream>>>(agg0, k1W, k1b, nullptr, q1, &sc[0], NP, 256, 256);
    gemm64<true><<<dim3(cdiv(NP, 64), 4), 256, 0, stream>>>(agg2, k1W, k1b, nullptr, q1, &sc[1], NP, 256, 256);
    gemm64<true><<<dim3(cdiv(NA, 64), 4), 256, 0, stream>>>(agg1, k1W, k1b, nullptr, q1, &sc[2], NA, 256, 256);
    gemm64<true><<<dim3(cdiv(NA, 64), 4), 256, 0, stream>>>(agg3, k1W, k1b, nullptr, q1, &sc[3], NA, 256, 256);
    softmax2<<<1, 1, 0, stream>>>(&sc[0], 1.f / NP, &sc[6]);
    softmax2<<<1, 1, 0, stream>>>(&sc[2], 1.f / NA, &sc[8]);
    combine2<<<cdiv(NP * D1 / 4, 256), 256, 0, stream>>>(agg0, agg2, &sc[6], res_p, NP * D1 / 4);
    combine2<<<cdiv(NA * D1 / 4, 256), 256, 0, stream>>>(agg1, agg3, &sc[8], res_a, NA * D1 / 4);

    // ---- 6. layer-2 transforms ----
    gemm64<false><<<dim3(cdiv(NA, 64), 2), 256, 0, stream>>>(res_a, W2a, b2a, h2a, nullptr, nullptr, NA, 256, 128);
    gemm64<false><<<dim3(cdiv(NP, 64), 2), 256, 0, stream>>>(res_p, W2p, b2p, h2p, nullptr, nullptr, NP, 256, 128);

    // ---- 7. layer-2 (author output only -> edge types 1: p->a, 3: a->a) ----
    node_scores<32><<<cdiv(NP * 4, 256), 256, 0, stream>>>(h2p, att2s + 1 * 128, ss21, NP);
    node_scores<32><<<cdiv(NA * 4, 256), 256, 0, stream>>>(h2a, att2d + 1 * 128, sd21, NA);
    node_scores<32><<<cdiv(NA * 4, 256), 256, 0, stream>>>(h2a, att2s + 3 * 128, ss23, NA);
    node_scores<32><<<cdiv(NA * 4, 256), 256, 0, stream>>>(h2a, att2d + 3 * 128, sd23, NA);
    agg_norm<128><<<cdiv(NA, 4), 256, 0, stream>>>(h2p, ss21, sd21, src[1], rp[1], eid[1], g21, NA);
    agg_norm<128><<<cdiv(NA, 4), 256, 0, stream>>>(h2a, ss23, sd23, src[3], rp[3], eid[3], g23, NA);

    // ---- 8. layer-2 semantic attention (author) -> d_out ----
    gemm64<true><<<dim3(cdiv(NA, 64), 2), 256, 0, stream>>>(g21, k2W, k2b, nullptr, q2, &sc[4], NA, 128, 128);
    gemm64<true><<<dim3(cdiv(NA, 64), 2), 256, 0, stream>>>(g23, k2W, k2b, nullptr, q2, &sc[5], NA, 128, 128);
    softmax2<<<1, 1, 0, stream>>>(&sc[4], 1.f / NA, &sc[10]);
    combine2<<<cdiv(NA * D2 / 4, 256), 256, 0, stream>>>(g21, g23, &sc[10], (float*)d_out, NA * D2 / 4);
}

// Round 2
// 982.628 us; speedup vs baseline: 1.2859x; 1.2859x over previous
//
#include <hip/hip_runtime.h>
#include <math.h>

// HAN (2-layer) on MI355X.
// GEMMs via split-bf16 MFMA (3-product emulation ~ f32 precision).
// Layer-2 computes only what the author output needs (edge types 1,3).

#define NA 20000
#define NP 30000
#define NE 200000
#define D1 256   // HID
#define D2 128   // OUT

typedef __attribute__((ext_vector_type(8))) short short8v;
typedef __attribute__((ext_vector_type(4))) short short4v;
typedef __attribute__((ext_vector_type(4))) float floatx4;

static __device__ __forceinline__ float lrelu(float x) { return x >= 0.f ? x : 0.2f * x; }

// truncating f32 -> bf16 bits (error captured by the lo term of the split)
static __device__ __forceinline__ unsigned short bftrunc(float x) {
    return (unsigned short)(__float_as_uint(x) >> 16);
}
static __device__ __forceinline__ float bf2f(unsigned short b) {
    return __uint_as_float(((unsigned)b) << 16);
}

// ---------------- CSR build ----------------
__global__ void count_deg(const int* __restrict__ dstv, int* __restrict__ cnt, int n) {
    int i = blockIdx.x * blockDim.x + threadIdx.x;
    if (i < n) atomicAdd(&cnt[dstv[i]], 1);
}

__global__ void fill_csr(const int* __restrict__ dstv, int* __restrict__ cursor,
                         int* __restrict__ eidv, int n) {
    int i = blockIdx.x * blockDim.x + threadIdx.x;
    if (i < n) { int p = atomicAdd(&cursor[dstv[i]], 1); eidv[p] = i; }
}

// single-block exclusive scan (n ~ 30000); writes rowptr[0..n] and cursor copy.
__global__ __launch_bounds__(1024) void exscan(const int* __restrict__ in,
                                               int* __restrict__ rowptr,
                                               int* __restrict__ cursor, int n) {
    __shared__ int buf[2][1024];
    __shared__ int carry_s;
    const int t = threadIdx.x;
    if (t == 0) carry_s = 0;
    __syncthreads();
    for (int base = 0; base < n; base += 1024) {
        int i = base + t;
        int v = (i < n) ? in[i] : 0;
        int cur = 0;
        buf[0][t] = v;
        __syncthreads();
        for (int off = 1; off < 1024; off <<= 1) {
            int add = (t >= off) ? buf[cur][t - off] : 0;
            buf[cur ^ 1][t] = buf[cur][t] + add;
            cur ^= 1;
            __syncthreads();
        }
        int incl = buf[cur][t];
        int carry = carry_s;
        if (i < n) { int ex = carry + incl - v; rowptr[i] = ex; cursor[i] = ex; }
        __syncthreads();
        if (t == 1023) carry_s = carry + incl;
        __syncthreads();
    }
    if (t == 0) rowptr[n] = carry_s;
}

// ---------------- split-bf16 MFMA GEMM ----------------
// C[M,BN] = A[M,K] @ W[K,BN] (+bias). BN == N always (one x-dim grid).
// SCORE=true: atomicAdd(score_out, sum_{n<M,f} tanh(C[n][f]+bias[f])*qv[f])
// 4 waves/block; wave tile 64x64; A split on the fly; W transposed+split into LDS.
template <int BN, bool SCORE>
__global__ __launch_bounds__(256) void gemm_mfma(
    const float* __restrict__ A, const float* __restrict__ W,
    const float* __restrict__ bias, float* __restrict__ C,
    const float* __restrict__ qv, float* __restrict__ score_out,
    int M, int K) {
    constexpr int WGN = BN / 64;      // waves along N: 4 (BN=256) or 2 (BN=128)
    constexpr int WGM = 4 / WGN;      // waves along M: 1 or 2
    constexpr int BM = WGM * 64;      // 64 or 128
    constexpr int LDK = 40;           // padded k-stride: 80B rows -> 16B-aligned, 2-way banks
    constexpr int KPT = BN / 8;       // W f32 elements per thread per k-step
    __shared__ unsigned short As[2][BM][LDK];   // [hi/lo][row][k]
    __shared__ unsigned short Bs[2][BN][LDK];   // [hi/lo][col][k]  (W^T)
    const int t = threadIdx.x;
    const int lane = t & 63, wid = t >> 6;
    const int wr = wid / WGN, wc = wid % WGN;
    const int bm = blockIdx.x * BM;
    const int fq = lane >> 4, fr = lane & 15;
    const int bn_ = t % BN;
    const int kb_ = (t / BN) * KPT;
    floatx4 acc[4][4];
#pragma unroll
    for (int i = 0; i < 4; ++i)
#pragma unroll
        for (int j = 0; j < 4; ++j) acc[i][j] = {0.f, 0.f, 0.f, 0.f};

    for (int kt = 0; kt < K; kt += 32) {
        // ---- stage A tile (BM x 32 f32), split hi/lo ----
#pragma unroll
        for (int i = 0; i < BM / 32; ++i) {
            const int fi = t + 256 * i;
            const int row = fi >> 3, k4 = (fi & 7) * 4;
            const int gr = bm + row;
            float4 v = {0.f, 0.f, 0.f, 0.f};
            if (gr < M) v = *(const float4*)&A[(size_t)gr * K + kt + k4];
            const float xs4[4] = {v.x, v.y, v.z, v.w};
            short4v hi, lo;
#pragma unroll
            for (int k = 0; k < 4; ++k) {
                const unsigned short h = bftrunc(xs4[k]);
                hi[k] = (short)h;
                lo[k] = (short)bftrunc(xs4[k] - bf2f(h));
            }
            *(short4v*)&As[0][row][k4] = hi;
            *(short4v*)&As[1][row][k4] = lo;
        }
        // ---- stage W tile (32 x BN f32) transposed into Bs[col][k], split hi/lo ----
        // reads are coalesced (all lanes sweep one W row); writes are b128, 2-way banks
#pragma unroll
        for (int w = 0; w < KPT / 8; ++w) {
            short8v hi, lo;
#pragma unroll
            for (int k = 0; k < 8; ++k) {
                const float x = W[(size_t)(kt + kb_ + w * 8 + k) * BN + bn_];
                const unsigned short h = bftrunc(x);
                hi[k] = (short)h;
                lo[k] = (short)bftrunc(x - bf2f(h));
            }
            *(short8v*)&Bs[0][bn_][kb_ + w * 8] = hi;
            *(short8v*)&Bs[1][bn_][kb_ + w * 8] = lo;
        }
        __syncthreads();
        // ---- fragments: 8 k-contiguous bf16 per lane; M/N index = lane&15 ----
        short8v ah[4], al[4], bh[4], bl[4];
#pragma unroll
        for (int f = 0; f < 4; ++f) {
            const int ar = wr * 64 + f * 16 + fr;
            ah[f] = *(const short8v*)&As[0][ar][fq * 8];
            al[f] = *(const short8v*)&As[1][ar][fq * 8];
            const int bc = wc * 64 + f * 16 + fr;
            bh[f] = *(const short8v*)&Bs[0][bc][fq * 8];
            bl[f] = *(const short8v*)&Bs[1][bc][fq * 8];
        }
#pragma unroll
        for (int i = 0; i < 4; ++i)
#pragma unroll
            for (int j = 0; j < 4; ++j) {
                acc[i][j] = __builtin_amdgcn_mfma_f32_16x16x32_bf16(ah[i], bh[j], acc[i][j], 0, 0, 0);
                acc[i][j] = __builtin_amdgcn_mfma_f32_16x16x32_bf16(ah[i], bl[j], acc[i][j], 0, 0, 0);
                acc[i][j] = __builtin_amdgcn_mfma_f32_16x16x32_bf16(al[i], bh[j], acc[i][j], 0, 0, 0);
            }
        __syncthreads();
    }
    // ---- epilogue; C/D layout (m89-verified): row=(lane>>4)*4+reg, col=lane&15 ----
    if constexpr (!SCORE) {
#pragma unroll
        for (int i = 0; i < 4; ++i) {
            const int gr0 = bm + wr * 64 + i * 16 + fq * 4;
#pragma unroll
            for (int j = 0; j < 4; ++j) {
                const int col = wc * 64 + j * 16 + fr;
                const float b = bias[col];
#pragma unroll
                for (int r = 0; r < 4; ++r) {
                    const int gr = gr0 + r;
                    if (gr < M) C[(size_t)gr * BN + col] = acc[i][j][r] + b;
                }
            }
        }
    } else {
        __shared__ float red[256];
        float partial = 0.f;
#pragma unroll
        for (int i = 0; i < 4; ++i) {
            const int gr0 = bm + wr * 64 + i * 16 + fq * 4;
#pragma unroll
            for (int j = 0; j < 4; ++j) {
                const int col = wc * 64 + j * 16 + fr;
                const float b = bias[col], q = qv[col];
#pragma unroll
                for (int r = 0; r < 4; ++r) {
                    if (gr0 + r < M) partial += tanhf(acc[i][j][r] + b) * q;
                }
            }
        }
        red[t] = partial;
        __syncthreads();
        for (int s = 128; s > 0; s >>= 1) {
            if (t < s) red[t] += red[t + s];
            __syncthreads();
        }
        if (t == 0) atomicAdd(score_out, red[0]);
    }
}

// ---------------- per-node attention scalars: s[n,h] = <h[n,h,:], att[h,:]> ----------------
template <int HD>
__global__ __launch_bounds__(256) void node_scores(const float* __restrict__ h,
                                                   const float* __restrict__ att,
                                                   float* __restrict__ s, int n) {
    const int idx = blockIdx.x * blockDim.x + threadIdx.x;
    const int node = idx >> 2, hh = idx & 3;
    if (node >= n) return;
    const float* row = h + (size_t)node * (4 * HD) + hh * HD;
    const float* ar = att + hh * HD;
    float acc = 0.f;
#pragma unroll
    for (int d = 0; d < HD; d += 4) {
        float4 x = *(const float4*)&row[d];
        float4 a = *(const float4*)&ar[d];
        acc = fmaf(x.x, a.x, acc); acc = fmaf(x.y, a.y, acc);
        acc = fmaf(x.z, a.z, acc); acc = fmaf(x.w, a.w, acc);
    }
    s[idx] = acc;
}

// ---------------- fused segment softmax + weighted aggregation + relu ----------------
template <int D>
__global__ __launch_bounds__(256) void agg_norm(
    const float* __restrict__ xs, const float* __restrict__ ssrc,
    const float* __restrict__ sdst, const int* __restrict__ srcIdx,
    const int* __restrict__ rowptr, const int* __restrict__ eidv,
    float* __restrict__ out, int n_dst) {
    constexpr int VPL = D / 64;
    const int wid = (int)((blockIdx.x * (size_t)blockDim.x + threadIdx.x) >> 6);
    const int lane = threadIdx.x & 63;
    if (wid >= n_dst) return;
    const int e0 = rowptr[wid], e1 = rowptr[wid + 1];
    const int h = lane >> 4;
    const float4 sdv = *(const float4*)&sdst[wid * 4];
    const float sdh[4] = {sdv.x, sdv.y, sdv.z, sdv.w};
    float mx[4] = {-INFINITY, -INFINITY, -INFINITY, -INFINITY};
    for (int e = e0 + lane; e < e1; e += 64) {
        const int r = srcIdx[eidv[e]];
        const float4 ssv = *(const float4*)&ssrc[r * 4];
        const float ss4[4] = {ssv.x, ssv.y, ssv.z, ssv.w};
#pragma unroll
        for (int k = 0; k < 4; ++k) mx[k] = fmaxf(mx[k], lrelu(ss4[k] + sdh[k]));
    }
#pragma unroll
    for (int k = 0; k < 4; ++k) {
#pragma unroll
        for (int off = 32; off > 0; off >>= 1) mx[k] = fmaxf(mx[k], __shfl_xor(mx[k], off));
    }
    const float myMax = mx[h], mySd = sdh[h];
    float acc[VPL] = {};
    float denom = 0.f;
    for (int e = e0; e < e1; ++e) {
        const int r = srcIdx[eidv[e]];
        const float a = lrelu(ssrc[r * 4 + h] + mySd);
        const float ea = expf(a - myMax);
        denom += ea;
        const float* xr = xs + (size_t)r * D + lane * VPL;
        if constexpr (VPL == 4) {
            float4 x = *(const float4*)xr;
            acc[0] += x.x * ea; acc[1] += x.y * ea; acc[2] += x.z * ea; acc[3] += x.w * ea;
        } else {
            float2 x = *(const float2*)xr;
            acc[0] += x.x * ea; acc[1] += x.y * ea;
        }
    }
    const float inv = 1.f / (denom + 1e-16f);
    float* orow = out + (size_t)wid * D + lane * VPL;
    if constexpr (VPL == 4) {
        float4 o = {fmaxf(acc[0] * inv, 0.f), fmaxf(acc[1] * inv, 0.f),
                    fmaxf(acc[2] * inv, 0.f), fmaxf(acc[3] * inv, 0.f)};
        *(float4*)orow = o;
    } else {
        float2 o = {fmaxf(acc[0] * inv, 0.f), fmaxf(acc[1] * inv, 0.f)};
        *(float2*)orow = o;
    }
}

// ---------------- semantic softmax (M=2) + combine ----------------
__global__ void softmax2(const float* __restrict__ score, float invN, float* __restrict__ attn) {
    const float s0 = score[0] * invN, s1 = score[1] * invN;
    const float m = fmaxf(s0, s1);
    const float e0 = expf(s0 - m), e1 = expf(s1 - m);
    const float d = e0 + e1;
    attn[0] = e0 / d;
    attn[1] = e1 / d;
}

__global__ __launch_bounds__(256) void combine2(const float* __restrict__ a,
                                                const float* __restrict__ b,
                                                const float* __restrict__ attn,
                                                float* __restrict__ out, int n4) {
    const int i = blockIdx.x * blockDim.x + threadIdx.x;
    if (i >= n4) return;
    const float w0 = attn[0], w1 = attn[1];
    float4 x = ((const float4*)a)[i], y = ((const float4*)b)[i];
    float4 o = {w0 * x.x + w1 * y.x, w0 * x.y + w1 * y.y,
                w0 * x.z + w1 * y.z, w0 * x.w + w1 * y.w};
    ((float4*)out)[i] = o;
}

static inline int cdiv(int a, int b) { return (a + b - 1) / b; }

extern "C" void kernel_launch(void* const* d_in, const int* in_sizes, int n_in,
                              void* d_out, int out_size, void* d_ws, size_t ws_size,
                              hipStream_t stream) {
    const float* x_a = (const float*)d_in[0];
    const float* x_p = (const float*)d_in[1];
    const int* src[4] = {(const int*)d_in[2], (const int*)d_in[4], (const int*)d_in[6], (const int*)d_in[8]};
    const int* dst[4] = {(const int*)d_in[3], (const int*)d_in[5], (const int*)d_in[7], (const int*)d_in[9]};
    const float* W1a = (const float*)d_in[10]; const float* b1a = (const float*)d_in[11];
    const float* W1p = (const float*)d_in[12]; const float* b1p = (const float*)d_in[13];
    const float* att1s = (const float*)d_in[14]; const float* att1d = (const float*)d_in[15];
    const float* q1 = (const float*)d_in[16];
    const float* k1W = (const float*)d_in[17]; const float* k1b = (const float*)d_in[18];
    const float* W2a = (const float*)d_in[19]; const float* b2a = (const float*)d_in[20];
    const float* W2p = (const float*)d_in[21]; const float* b2p = (const float*)d_in[22];
    const float* att2s = (const float*)d_in[23]; const float* att2d = (const float*)d_in[24];
    const float* q2 = (const float*)d_in[25];
    const float* k2W = (const float*)d_in[26]; const float* k2b = (const float*)d_in[27];

    // ---- workspace layout (floats), with lifetime-based reuse ----
    float* ws = (float*)d_ws;
    float* h1a = ws;                                  // [NA,256]
    float* h1p = h1a + (size_t)NA * D1;               // [NP,256]
    float* agg0 = h1p + (size_t)NP * D1;              // [NP,256] a->p
    float* agg1 = agg0 + (size_t)NP * D1;             // [NA,256] p->a
    float* agg2 = agg1 + (size_t)NA * D1;             // [NP,256] p->p
    float* agg3 = agg2 + (size_t)NP * D1;             // [NA,256] a->a
    float* sv = agg3 + (size_t)NA * D1;               // per-type per-node attention scalars
    float* ss0 = sv;            float* sd0 = ss0 + NA * 4;
    float* ss1 = sd0 + NP * 4;  float* sd1 = ss1 + NP * 4;
    float* ss2 = sd1 + NA * 4;  float* sd2 = ss2 + NP * 4;
    float* ss3 = sd2 + NP * 4;  float* sd3 = ss3 + NA * 4;
    float* sc = sd3 + NA * 4;   // 16 floats of scores/attn
    int* csr = (int*)(sc + 16);
    const int nd[4] = {NP, NA, NP, NA};
    int* rp[4]; int* cur[4]; int* eid[4];
    int* p = csr;
    for (int i = 0; i < 4; ++i) { rp[i] = p; p += nd[i] + 1; }
    int* cur0 = p;
    for (int i = 0; i < 4; ++i) { cur[i] = p; p += nd[i]; }
    for (int i = 0; i < 4; ++i) { eid[i] = p; p += NE; }
    const size_t need_bytes = (size_t)((char*)p - (char*)d_ws);
    if (ws_size < need_bytes) return;

    // region reuse after layer-1 aggregation:
    float* res_a = h1a;   // [NA,256]
    float* res_p = h1p;   // [NP,256]
    float* h2a = agg0;    // [NA,128]
    float* h2p = agg2;    // [NP,128]
    float* g21 = agg1;    // [NA,128] layer2 p->a
    float* g23 = agg3;    // [NA,128] layer2 a->a
    float* ss21 = sv;            float* sd21 = ss21 + NP * 4;
    float* ss23 = sd21 + NA * 4; float* sd23 = ss23 + NA * 4;

    // ---- 0. zero accumulators ----
    hipMemsetAsync(cur0, 0, (size_t)(NP + NA + NP + NA) * sizeof(int), stream);
    hipMemsetAsync(sc, 0, 16 * sizeof(float), stream);

    // ---- 1. CSR build (edge sets shared by both layers) ----
    for (int i = 0; i < 4; ++i)
        count_deg<<<cdiv(NE, 256), 256, 0, stream>>>(dst[i], cur[i], NE);
    for (int i = 0; i < 4; ++i)
        exscan<<<1, 1024, 0, stream>>>(cur[i], rp[i], cur[i], nd[i]);
    for (int i = 0; i < 4; ++i)
        fill_csr<<<cdiv(NE, 256), 256, 0, stream>>>(dst[i], cur[i], eid[i], NE);

    // ---- 2. layer-1 transforms (split-bf16 MFMA) ----
    gemm_mfma<256, false><<<cdiv(NA, 64), 256, 0, stream>>>(x_a, W1a, b1a, h1a, nullptr, nullptr, NA, 256);
    gemm_mfma<256, false><<<cdiv(NP, 64), 256, 0, stream>>>(x_p, W1p, b1p, h1p, nullptr, nullptr, NP, 256);

    // ---- 3. per-node attention scalars (layer 1) ----
    node_scores<64><<<cdiv(NA * 4, 256), 256, 0, stream>>>(h1a, att1s + 0 * 256, ss0, NA);
    node_scores<64><<<cdiv(NP * 4, 256), 256, 0, stream>>>(h1p, att1d + 0 * 256, sd0, NP);
    node_scores<64><<<cdiv(NP * 4, 256), 256, 0, stream>>>(h1p, att1s + 1 * 256, ss1, NP);
    node_scores<64><<<cdiv(NA * 4, 256), 256, 0, stream>>>(h1a, att1d + 1 * 256, sd1, NA);
    node_scores<64><<<cdiv(NP * 4, 256), 256, 0, stream>>>(h1p, att1s + 2 * 256, ss2, NP);
    node_scores<64><<<cdiv(NP * 4, 256), 256, 0, stream>>>(h1p, att1d + 2 * 256, sd2, NP);
    node_scores<64><<<cdiv(NA * 4, 256), 256, 0, stream>>>(h1a, att1s + 3 * 256, ss3, NA);
    node_scores<64><<<cdiv(NA * 4, 256), 256, 0, stream>>>(h1a, att1d + 3 * 256, sd3, NA);

    // ---- 4. layer-1 fused segment-softmax aggregation ----
    agg_norm<256><<<cdiv(NP, 4), 256, 0, stream>>>(h1a, ss0, sd0, src[0], rp[0], eid[0], agg0, NP);
    agg_norm<256><<<cdiv(NA, 4), 256, 0, stream>>>(h1p, ss1, sd1, src[1], rp[1], eid[1], agg1, NA);
    agg_norm<256><<<cdiv(NP, 4), 256, 0, stream>>>(h1p, ss2, sd2, src[2], rp[2], eid[2], agg2, NP);
    agg_norm<256><<<cdiv(NA, 4), 256, 0, stream>>>(h1a, ss3, sd3, src[3], rp[3], eid[3], agg3, NA);

    // ---- 5. semantic scores (layer 1) ----
    gemm_mfma<256, true><<<cdiv(NP, 64), 256, 0, stream>>>(agg0, k1W, k1b, nullptr, q1, &sc[0], NP, 256);
    gemm_mfma<256, true><<<cdiv(NP, 64), 256, 0, stream>>>(agg2, k1W, k1b, nullptr, q1, &sc[1], NP, 256);
    gemm_mfma<256, true><<<cdiv(NA, 64), 256, 0, stream>>>(agg1, k1W, k1b, nullptr, q1, &sc[2], NA, 256);
    gemm_mfma<256, true><<<cdiv(NA, 64), 256, 0, stream>>>(agg3, k1W, k1b, nullptr, q1, &sc[3], NA, 256);
    softmax2<<<1, 1, 0, stream>>>(&sc[0], 1.f / NP, &sc[6]);
    softmax2<<<1, 1, 0, stream>>>(&sc[2], 1.f / NA, &sc[8]);
    combine2<<<cdiv(NP * D1 / 4, 256), 256, 0, stream>>>(agg0, agg2, &sc[6], res_p, NP * D1 / 4);
    combine2<<<cdiv(NA * D1 / 4, 256), 256, 0, stream>>>(agg1, agg3, &sc[8], res_a, NA * D1 / 4);

    // ---- 6. layer-2 transforms ----
    gemm_mfma<128, false><<<cdiv(NA, 128), 256, 0, stream>>>(res_a, W2a, b2a, h2a, nullptr, nullptr, NA, 256);
    gemm_mfma<128, false><<<cdiv(NP, 128), 256, 0, stream>>>(res_p, W2p, b2p, h2p, nullptr, nullptr, NP, 256);

    // ---- 7. layer-2 (author output only -> edge types 1: p->a, 3: a->a) ----
    node_scores<32><<<cdiv(NP * 4, 256), 256, 0, stream>>>(h2p, att2s + 1 * 128, ss21, NP);
    node_scores<32><<<cdiv(NA * 4, 256), 256, 0, stream>>>(h2a, att2d + 1 * 128, sd21, NA);
    node_scores<32><<<cdiv(NA * 4, 256), 256, 0, stream>>>(h2a, att2s + 3 * 128, ss23, NA);
    node_scores<32><<<cdiv(NA * 4, 256), 256, 0, stream>>>(h2a, att2d + 3 * 128, sd23, NA);
    agg_norm<128><<<cdiv(NA, 4), 256, 0, stream>>>(h2p, ss21, sd21, src[1], rp[1], eid[1], g21, NA);
    agg_norm<128><<<cdiv(NA, 4), 256, 0, stream>>>(h2a, ss23, sd23, src[3], rp[3], eid[3], g23, NA);

    // ---- 8. layer-2 semantic attention (author) -> d_out ----
    gemm_mfma<128, true><<<cdiv(NA, 128), 256, 0, stream>>>(g21, k2W, k2b, nullptr, q2, &sc[4], NA, 128);
    gemm_mfma<128, true><<<cdiv(NA, 128), 256, 0, stream>>>(g23, k2W, k2b, nullptr, q2, &sc[5], NA, 128);
    softmax2<<<1, 1, 0, stream>>>(&sc[4], 1.f / NA, &sc[10]);
    combine2<<<cdiv(NA * D2 / 4, 256), 256, 0, stream>>>(g21, g23, &sc[10], (float*)d_out, NA * D2 / 4);
}

// Round 3
// 723.017 us; speedup vs baseline: 1.7477x; 1.3591x over previous
//
#include <hip/hip_runtime.h>
#include <math.h>

// HAN (2-layer) on MI355X.
// GEMMs via split-bf16 MFMA; features stored bf16 for gather; CSR gather with
// precomputed per-edge logits. Layer-2 computes only author-needed work.

#define NA 20000
#define NP 30000
#define NE 200000
#define D1 256   // HID
#define D2 128   // OUT

typedef __attribute__((ext_vector_type(8))) short short8v;
typedef __attribute__((ext_vector_type(4))) short short4v;
typedef __attribute__((ext_vector_type(4))) float floatx4;
typedef __attribute__((ext_vector_type(4))) unsigned short ushort4v;
typedef __attribute__((ext_vector_type(2))) unsigned short ushort2v;

static __device__ __forceinline__ float lrelu(float x) { return x >= 0.f ? x : 0.2f * x; }

static __device__ __forceinline__ unsigned short bftrunc(float x) {
    return (unsigned short)(__float_as_uint(x) >> 16);
}
static __device__ __forceinline__ float bf2f(unsigned short b) {
    return __uint_as_float(((unsigned)b) << 16);
}
// round-to-nearest-even f32 -> bf16
static __device__ __forceinline__ unsigned short bfrn(float x) {
    unsigned u = __float_as_uint(x);
    return (unsigned short)((u + 0x7FFFu + ((u >> 16) & 1u)) >> 16);
}
static __device__ __forceinline__ float pick4(float4 v, int h) {
    float ab = (h & 1) ? v.y : v.x;
    float cd = (h & 1) ? v.w : v.z;
    return (h & 2) ? cd : ab;
}

// ---------------- CSR build ----------------
__global__ void count_deg(const int* __restrict__ dstv, int* __restrict__ cnt, int n) {
    int i = blockIdx.x * blockDim.x + threadIdx.x;
    if (i < n) atomicAdd(&cnt[dstv[i]], 1);
}

__global__ void fill_csr(const int* __restrict__ srcv, const int* __restrict__ dstv,
                         int* __restrict__ cursor, int* __restrict__ csrc,
                         int* __restrict__ cdst, int n) {
    int i = blockIdx.x * blockDim.x + threadIdx.x;
    if (i < n) {
        int d = dstv[i];
        int p = atomicAdd(&cursor[d], 1);
        csrc[p] = srcv[i];
        cdst[p] = d;
    }
}

// 4 edge-type exclusive scans in one launch (blockIdx = type), wave-shuffle based.
__global__ __launch_bounds__(1024) void exscan4(int* __restrict__ curbase,
                                                int* __restrict__ rpbase) {
    const int off_c[4] = {0, NP, NP + NA, NP + NA + NP};
    const int off_r[4] = {0, NP + 1, NP + NA + 2, NP + NA + NP + 3};
    const int ns[4] = {NP, NA, NP, NA};
    const int b = blockIdx.x;
    int* cur = curbase + off_c[b];
    int* rp = rpbase + off_r[b];
    const int n = ns[b];
    __shared__ int wsum[16];
    __shared__ int carry_s;
    const int t = threadIdx.x, wv = t >> 6, ln = t & 63;
    if (t == 0) carry_s = 0;
    __syncthreads();
    for (int base = 0; base < n; base += 1024) {
        const int i = base + t;
        const int v = (i < n) ? cur[i] : 0;
        int x = v;
#pragma unroll
        for (int off = 1; off < 64; off <<= 1) {
            int y = __shfl_up(x, off);
            if (ln >= off) x += y;
        }
        if (ln == 63) wsum[wv] = x;
        __syncthreads();
        if (wv == 0) {
            int s = (ln < 16) ? wsum[ln] : 0;
#pragma unroll
            for (int off = 1; off < 16; off <<= 1) {
                int y = __shfl_up(s, off);
                if (ln >= off) s += y;
            }
            if (ln < 16) wsum[ln] = s;
        }
        __syncthreads();
        const int woff = (wv == 0) ? 0 : wsum[wv - 1];
        const int c = carry_s;
        const int ex = c + woff + x - v;
        if (i < n) { rp[i] = ex; cur[i] = ex; }
        __syncthreads();
        if (t == 1023) carry_s = c + wsum[15];
        __syncthreads();
    }
    if (t == 0) rp[n] = carry_s;
}

// ---------------- split-bf16 MFMA GEMM ----------------
// SCORE=false: Cb[M,BN] = bf16_rn(A@W + bias)
// SCORE=true : atomicAdd(score_out, sum tanh(C+bias)*qv)
template <int BN, bool SCORE>
__global__ __launch_bounds__(256) void gemm_mfma(
    const float* __restrict__ A, const float* __restrict__ W,
    const float* __restrict__ bias, unsigned short* __restrict__ Cb,
    const float* __restrict__ qv, float* __restrict__ score_out,
    int M, int K) {
    constexpr int WGN = BN / 64;
    constexpr int WGM = 4 / WGN;
    constexpr int BM = WGM * 64;
    constexpr int LDK = 40;
    constexpr int KPT = BN / 8;
    __shared__ unsigned short As[2][BM][LDK];
    __shared__ unsigned short Bs[2][BN][LDK];
    const int t = threadIdx.x;
    const int lane = t & 63, wid = t >> 6;
    const int wr = wid / WGN, wc = wid % WGN;
    const int bm = blockIdx.x * BM;
    const int fq = lane >> 4, fr = lane & 15;
    const int bn_ = t % BN;
    const int kb_ = (t / BN) * KPT;
    floatx4 acc[4][4];
#pragma unroll
    for (int i = 0; i < 4; ++i)
#pragma unroll
        for (int j = 0; j < 4; ++j) acc[i][j] = {0.f, 0.f, 0.f, 0.f};

    for (int kt = 0; kt < K; kt += 32) {
#pragma unroll
        for (int i = 0; i < BM / 32; ++i) {
            const int fi = t + 256 * i;
            const int row = fi >> 3, k4 = (fi & 7) * 4;
            const int gr = bm + row;
            float4 v = {0.f, 0.f, 0.f, 0.f};
            if (gr < M) v = *(const float4*)&A[(size_t)gr * K + kt + k4];
            const float xs4[4] = {v.x, v.y, v.z, v.w};
            short4v hi, lo;
#pragma unroll
            for (int k = 0; k < 4; ++k) {
                const unsigned short hb = bftrunc(xs4[k]);
                hi[k] = (short)hb;
                lo[k] = (short)bftrunc(xs4[k] - bf2f(hb));
            }
            *(short4v*)&As[0][row][k4] = hi;
            *(short4v*)&As[1][row][k4] = lo;
        }
#pragma unroll
        for (int w = 0; w < KPT / 8; ++w) {
            short8v hi, lo;
#pragma unroll
            for (int k = 0; k < 8; ++k) {
                const float x = W[(size_t)(kt + kb_ + w * 8 + k) * BN + bn_];
                const unsigned short hb = bftrunc(x);
                hi[k] = (short)hb;
                lo[k] = (short)bftrunc(x - bf2f(hb));
            }
            *(short8v*)&Bs[0][bn_][kb_ + w * 8] = hi;
            *(short8v*)&Bs[1][bn_][kb_ + w * 8] = lo;
        }
        __syncthreads();
        short8v ah[4], al[4], bh[4], bl[4];
#pragma unroll
        for (int f = 0; f < 4; ++f) {
            const int ar = wr * 64 + f * 16 + fr;
            ah[f] = *(const short8v*)&As[0][ar][fq * 8];
            al[f] = *(const short8v*)&As[1][ar][fq * 8];
            const int bc = wc * 64 + f * 16 + fr;
            bh[f] = *(const short8v*)&Bs[0][bc][fq * 8];
            bl[f] = *(const short8v*)&Bs[1][bc][fq * 8];
        }
#pragma unroll
        for (int i = 0; i < 4; ++i)
#pragma unroll
            for (int j = 0; j < 4; ++j) {
                acc[i][j] = __builtin_amdgcn_mfma_f32_16x16x32_bf16(ah[i], bh[j], acc[i][j], 0, 0, 0);
                acc[i][j] = __builtin_amdgcn_mfma_f32_16x16x32_bf16(ah[i], bl[j], acc[i][j], 0, 0, 0);
                acc[i][j] = __builtin_amdgcn_mfma_f32_16x16x32_bf16(al[i], bh[j], acc[i][j], 0, 0, 0);
            }
        __syncthreads();
    }
    if constexpr (!SCORE) {
#pragma unroll
        for (int i = 0; i < 4; ++i) {
            const int gr0 = bm + wr * 64 + i * 16 + fq * 4;
#pragma unroll
            for (int j = 0; j < 4; ++j) {
                const int col = wc * 64 + j * 16 + fr;
                const float b = bias[col];
#pragma unroll
                for (int r = 0; r < 4; ++r) {
                    const int gr = gr0 + r;
                    if (gr < M) Cb[(size_t)gr * BN + col] = bfrn(acc[i][j][r] + b);
                }
            }
        }
    } else {
        __shared__ float red[256];
        float partial = 0.f;
#pragma unroll
        for (int i = 0; i < 4; ++i) {
            const int gr0 = bm + wr * 64 + i * 16 + fq * 4;
#pragma unroll
            for (int j = 0; j < 4; ++j) {
                const int col = wc * 64 + j * 16 + fr;
                const float b = bias[col], q = qv[col];
#pragma unroll
                for (int r = 0; r < 4; ++r) {
                    if (gr0 + r < M) partial += tanhf(acc[i][j][r] + b) * q;
                }
            }
        }
        red[t] = partial;
        __syncthreads();
        for (int s = 128; s > 0; s >>= 1) {
            if (t < s) red[t] += red[t + s];
            __syncthreads();
        }
        if (t == 0) atomicAdd(score_out, red[0]);
    }
}

// ---------------- fused node attention-score dots (bf16 h, up to 4 att vectors) ----------------
template <int HD, int NSC>
__global__ __launch_bounds__(256) void node_scoresN(
    const unsigned short* __restrict__ hx,
    const float* __restrict__ a0, const float* __restrict__ a1,
    const float* __restrict__ a2, const float* __restrict__ a3,
    float* __restrict__ o0, float* __restrict__ o1,
    float* __restrict__ o2, float* __restrict__ o3, int n) {
    const int idx = blockIdx.x * blockDim.x + threadIdx.x;
    const int node = idx >> 2, hh = idx & 3;
    if (node >= n) return;
    const unsigned short* row = hx + (size_t)node * (4 * HD) + hh * HD;
    float s0 = 0.f, s1 = 0.f, s2 = 0.f, s3 = 0.f;
#pragma unroll
    for (int d = 0; d < HD; d += 4) {
        ushort4v xv = *(const ushort4v*)&row[d];
        const float x0 = bf2f(xv[0]), x1 = bf2f(xv[1]), x2 = bf2f(xv[2]), x3 = bf2f(xv[3]);
        float4 v = *(const float4*)&a0[hh * HD + d];
        s0 += x0 * v.x + x1 * v.y + x2 * v.z + x3 * v.w;
        if constexpr (NSC > 1) {
            v = *(const float4*)&a1[hh * HD + d];
            s1 += x0 * v.x + x1 * v.y + x2 * v.z + x3 * v.w;
        }
        if constexpr (NSC > 2) {
            v = *(const float4*)&a2[hh * HD + d];
            s2 += x0 * v.x + x1 * v.y + x2 * v.z + x3 * v.w;
        }
        if constexpr (NSC > 3) {
            v = *(const float4*)&a3[hh * HD + d];
            s3 += x0 * v.x + x1 * v.y + x2 * v.z + x3 * v.w;
        }
    }
    o0[idx] = s0;
    if constexpr (NSC > 1) o1[idx] = s1;
    if constexpr (NSC > 2) o2[idx] = s2;
    if constexpr (NSC > 3) o3[idx] = s3;
}

// ---------------- per-edge 4-head logits (CSR order, coalesced out) ----------------
__global__ __launch_bounds__(256) void edge_logits(
    const int* __restrict__ csrc, const int* __restrict__ cdst,
    const float* __restrict__ ss, const float* __restrict__ sd,
    float4* __restrict__ alog, int n) {
    int i = blockIdx.x * blockDim.x + threadIdx.x;
    if (i >= n) return;
    const int s = csrc[i], d = cdst[i];
    const float4 a = *(const float4*)&ss[s * 4];
    const float4 b = *(const float4*)&sd[d * 4];
    float4 o = {lrelu(a.x + b.x), lrelu(a.y + b.y), lrelu(a.z + b.z), lrelu(a.w + b.w)};
    alog[i] = o;
}

// ---------------- fused segment softmax + bf16 gather + relu ----------------
template <int D>
__global__ __launch_bounds__(256) void agg_bf(
    const unsigned short* __restrict__ xs, const float4* __restrict__ alog,
    const int* __restrict__ csrc, const int* __restrict__ rowptr,
    float* __restrict__ out, int n_dst) {
    constexpr int VPL = D / 64;
    const int wid = (int)((blockIdx.x * (size_t)blockDim.x + threadIdx.x) >> 6);
    const int lane = threadIdx.x & 63;
    if (wid >= n_dst) return;
    const int e0 = rowptr[wid], e1 = rowptr[wid + 1];
    const int h = lane >> 4;
    float mx[4] = {-INFINITY, -INFINITY, -INFINITY, -INFINITY};
    for (int e = e0 + lane; e < e1; e += 64) {
        const float4 l = alog[e];
        mx[0] = fmaxf(mx[0], l.x); mx[1] = fmaxf(mx[1], l.y);
        mx[2] = fmaxf(mx[2], l.z); mx[3] = fmaxf(mx[3], l.w);
    }
#pragma unroll
    for (int k = 0; k < 4; ++k) {
#pragma unroll
        for (int off = 32; off > 0; off >>= 1) mx[k] = fmaxf(mx[k], __shfl_xor(mx[k], off));
    }
    const float myMax = mx[h];
    float acc[VPL] = {};
    float denom = 0.f;
    int e = e0;
    for (; e + 2 <= e1; e += 2) {
        const int r0 = csrc[e], r1 = csrc[e + 1];
        const float4 l0 = alog[e], l1 = alog[e + 1];
        const float ea0 = __expf(pick4(l0, h) - myMax);
        const float ea1 = __expf(pick4(l1, h) - myMax);
        denom += ea0 + ea1;
        const unsigned short* p0 = xs + (size_t)r0 * D + lane * VPL;
        const unsigned short* p1 = xs + (size_t)r1 * D + lane * VPL;
        if constexpr (VPL == 4) {
            ushort4v x0 = *(const ushort4v*)p0;
            ushort4v x1 = *(const ushort4v*)p1;
#pragma unroll
            for (int k = 0; k < 4; ++k) acc[k] += bf2f(x0[k]) * ea0 + bf2f(x1[k]) * ea1;
        } else {
            ushort2v x0 = *(const ushort2v*)p0;
            ushort2v x1 = *(const ushort2v*)p1;
#pragma unroll
            for (int k = 0; k < 2; ++k) acc[k] += bf2f(x0[k]) * ea0 + bf2f(x1[k]) * ea1;
        }
    }
    if (e < e1) {
        const int r0 = csrc[e];
        const float4 l0 = alog[e];
        const float ea0 = __expf(pick4(l0, h) - myMax);
        denom += ea0;
        const unsigned short* p0 = xs + (size_t)r0 * D + lane * VPL;
        if constexpr (VPL == 4) {
            ushort4v x0 = *(const ushort4v*)p0;
#pragma unroll
            for (int k = 0; k < 4; ++k) acc[k] += bf2f(x0[k]) * ea0;
        } else {
            ushort2v x0 = *(const ushort2v*)p0;
#pragma unroll
            for (int k = 0; k < 2; ++k) acc[k] += bf2f(x0[k]) * ea0;
        }
    }
    const float inv = 1.f / (denom + 1e-16f);
    float* orow = out + (size_t)wid * D + lane * VPL;
    if constexpr (VPL == 4) {
        float4 o = {fmaxf(acc[0] * inv, 0.f), fmaxf(acc[1] * inv, 0.f),
                    fmaxf(acc[2] * inv, 0.f), fmaxf(acc[3] * inv, 0.f)};
        *(float4*)orow = o;
    } else {
        float2 o = {fmaxf(acc[0] * inv, 0.f), fmaxf(acc[1] * inv, 0.f)};
        *(float2*)orow = o;
    }
}

// ---------------- semantic softmax (M=2) + combine ----------------
__global__ void softmax2(const float* __restrict__ score, float invN, float* __restrict__ attn) {
    const float s0 = score[0] * invN, s1 = score[1] * invN;
    const float m = fmaxf(s0, s1);
    const float e0 = expf(s0 - m), e1 = expf(s1 - m);
    const float d = e0 + e1;
    attn[0] = e0 / d;
    attn[1] = e1 / d;
}

// out may alias a (elementwise same-index)
__global__ __launch_bounds__(256) void combine2(const float* __restrict__ a,
                                                const float* __restrict__ b,
                                                const float* __restrict__ attn,
                                                float* out, int n4) {
    const int i = blockIdx.x * blockDim.x + threadIdx.x;
    if (i >= n4) return;
    const float w0 = attn[0], w1 = attn[1];
    float4 x = ((const float4*)a)[i], y = ((const float4*)b)[i];
    float4 o = {w0 * x.x + w1 * y.x, w0 * x.y + w1 * y.y,
                w0 * x.z + w1 * y.z, w0 * x.w + w1 * y.w};
    ((float4*)out)[i] = o;
}

static inline int cdiv(int a, int b) { return (a + b - 1) / b; }

extern "C" void kernel_launch(void* const* d_in, const int* in_sizes, int n_in,
                              void* d_out, int out_size, void* d_ws, size_t ws_size,
                              hipStream_t stream) {
    const float* x_a = (const float*)d_in[0];
    const float* x_p = (const float*)d_in[1];
    const int* src[4] = {(const int*)d_in[2], (const int*)d_in[4], (const int*)d_in[6], (const int*)d_in[8]};
    const int* dst[4] = {(const int*)d_in[3], (const int*)d_in[5], (const int*)d_in[7], (const int*)d_in[9]};
    const float* W1a = (const float*)d_in[10]; const float* b1a = (const float*)d_in[11];
    const float* W1p = (const float*)d_in[12]; const float* b1p = (const float*)d_in[13];
    const float* att1s = (const float*)d_in[14]; const float* att1d = (const float*)d_in[15];
    const float* q1 = (const float*)d_in[16];
    const float* k1W = (const float*)d_in[17]; const float* k1b = (const float*)d_in[18];
    const float* W2a = (const float*)d_in[19]; const float* b2a = (const float*)d_in[20];
    const float* W2p = (const float*)d_in[21]; const float* b2p = (const float*)d_in[22];
    const float* att2s = (const float*)d_in[23]; const float* att2d = (const float*)d_in[24];
    const float* q2 = (const float*)d_in[25];
    const float* k2W = (const float*)d_in[26]; const float* k2b = (const float*)d_in[27];

    // ---- workspace layout ----
    char* wp = (char*)d_ws;
    unsigned short* h1a_bf = (unsigned short*)wp; wp += (size_t)NA * D1 * 2;
    unsigned short* h1p_bf = (unsigned short*)wp; wp += (size_t)NP * D1 * 2;
    float* agg0 = (float*)wp; wp += (size_t)NP * D1 * 4;
    float* agg1 = (float*)wp; wp += (size_t)NA * D1 * 4;
    float* agg2 = (float*)wp; wp += (size_t)NP * D1 * 4;
    float* agg3 = (float*)wp; wp += (size_t)NA * D1 * 4;
    float* sv = (float*)wp; wp += (size_t)(16 * NA + 16 * NP) * 4;
    float4* alogb = (float4*)wp; wp += (size_t)4 * NE * 16;
    float* sc = (float*)wp; wp += 16 * 4;
    int* rp_base = (int*)wp; wp += (size_t)(NP + NA + NP + NA + 4) * 4;
    int* cur_base = (int*)wp; wp += (size_t)(NP + NA + NP + NA) * 4;
    int* csrc_base = (int*)wp; wp += (size_t)4 * NE * 4;
    int* cdst_base = (int*)wp; wp += (size_t)4 * NE * 4;
    const size_t need_bytes = (size_t)(wp - (char*)d_ws);
    if (ws_size < need_bytes) return;

    // per-type views
    const int nd[4] = {NP, NA, NP, NA};
    int* rp[4] = {rp_base, rp_base + NP + 1, rp_base + NP + NA + 2, rp_base + NP + NA + NP + 3};
    int* cur[4] = {cur_base, cur_base + NP, cur_base + NP + NA, cur_base + NP + NA + NP};
    int* csrc[4]; int* cdst[4]; float4* alog[4];
    for (int i = 0; i < 4; ++i) {
        csrc[i] = csrc_base + (size_t)i * NE;
        cdst[i] = cdst_base + (size_t)i * NE;
        alog[i] = alogb + (size_t)i * NE;
    }
    // L1 score arrays
    float* ss0 = sv;             float* sd0 = ss0 + NA * 4;
    float* ss1 = sd0 + NP * 4;   float* sd1 = ss1 + NP * 4;
    float* ss2 = sd1 + NA * 4;   float* sd2 = ss2 + NP * 4;
    float* ss3 = sd2 + NP * 4;   float* sd3 = ss3 + NA * 4;
    // region reuse
    float* res_p = agg0;  // combine in-place
    float* res_a = agg1;
    unsigned short* h2a_bf = (unsigned short*)agg2;
    unsigned short* h2p_bf = h2a_bf + (size_t)NA * D2;
    float* g21 = agg3;
    float* g23 = agg3 + (size_t)NA * D2;
    float* ss21 = sv;             float* sd21 = ss21 + NP * 4;
    float* ss23 = sd21 + NA * 4;  float* sd23 = ss23 + NA * 4;

    // ---- 0. zero counters ----
    hipMemsetAsync(cur_base, 0, (size_t)(NP + NA + NP + NA) * sizeof(int), stream);
    hipMemsetAsync(sc, 0, 16 * sizeof(float), stream);

    // ---- 1. CSR build ----
    for (int i = 0; i < 4; ++i)
        count_deg<<<cdiv(NE, 256), 256, 0, stream>>>(dst[i], cur[i], NE);
    exscan4<<<4, 1024, 0, stream>>>(cur_base, rp_base);
    for (int i = 0; i < 4; ++i)
        fill_csr<<<cdiv(NE, 256), 256, 0, stream>>>(src[i], dst[i], cur[i], csrc[i], cdst[i], NE);

    // ---- 2. layer-1 transforms -> bf16 h ----
    gemm_mfma<256, false><<<cdiv(NA, 64), 256, 0, stream>>>(x_a, W1a, b1a, h1a_bf, nullptr, nullptr, NA, 256);
    gemm_mfma<256, false><<<cdiv(NP, 64), 256, 0, stream>>>(x_p, W1p, b1p, h1p_bf, nullptr, nullptr, NP, 256);

    // ---- 3. fused node attention scalars (layer 1) ----
    node_scoresN<64, 4><<<cdiv(NA * 4, 256), 256, 0, stream>>>(
        h1a_bf, att1s + 0 * 256, att1d + 1 * 256, att1s + 3 * 256, att1d + 3 * 256,
        ss0, sd1, ss3, sd3, NA);
    node_scoresN<64, 4><<<cdiv(NP * 4, 256), 256, 0, stream>>>(
        h1p_bf, att1d + 0 * 256, att1s + 1 * 256, att1s + 2 * 256, att1d + 2 * 256,
        sd0, ss1, ss2, sd2, NP);

    // ---- 4. per-edge logits, then fused aggregation ----
    edge_logits<<<cdiv(NE, 256), 256, 0, stream>>>(csrc[0], cdst[0], ss0, sd0, alog[0], NE);
    edge_logits<<<cdiv(NE, 256), 256, 0, stream>>>(csrc[1], cdst[1], ss1, sd1, alog[1], NE);
    edge_logits<<<cdiv(NE, 256), 256, 0, stream>>>(csrc[2], cdst[2], ss2, sd2, alog[2], NE);
    edge_logits<<<cdiv(NE, 256), 256, 0, stream>>>(csrc[3], cdst[3], ss3, sd3, alog[3], NE);
    agg_bf<256><<<cdiv(NP, 4), 256, 0, stream>>>(h1a_bf, alog[0], csrc[0], rp[0], agg0, NP);
    agg_bf<256><<<cdiv(NA, 4), 256, 0, stream>>>(h1p_bf, alog[1], csrc[1], rp[1], agg1, NA);
    agg_bf<256><<<cdiv(NP, 4), 256, 0, stream>>>(h1p_bf, alog[2], csrc[2], rp[2], agg2, NP);
    agg_bf<256><<<cdiv(NA, 4), 256, 0, stream>>>(h1a_bf, alog[3], csrc[3], rp[3], agg3, NA);

    // ---- 5. semantic scores (layer 1) + combine (in-place) ----
    gemm_mfma<256, true><<<cdiv(NP, 64), 256, 0, stream>>>(agg0, k1W, k1b, nullptr, q1, &sc[0], NP, 256);
    gemm_mfma<256, true><<<cdiv(NP, 64), 256, 0, stream>>>(agg2, k1W, k1b, nullptr, q1, &sc[1], NP, 256);
    gemm_mfma<256, true><<<cdiv(NA, 64), 256, 0, stream>>>(agg1, k1W, k1b, nullptr, q1, &sc[2], NA, 256);
    gemm_mfma<256, true><<<cdiv(NA, 64), 256, 0, stream>>>(agg3, k1W, k1b, nullptr, q1, &sc[3], NA, 256);
    softmax2<<<1, 1, 0, stream>>>(&sc[0], 1.f / NP, &sc[6]);
    softmax2<<<1, 1, 0, stream>>>(&sc[2], 1.f / NA, &sc[8]);
    combine2<<<cdiv(NP * D1 / 4, 256), 256, 0, stream>>>(agg0, agg2, &sc[6], res_p, NP * D1 / 4);
    combine2<<<cdiv(NA * D1 / 4, 256), 256, 0, stream>>>(agg1, agg3, &sc[8], res_a, NA * D1 / 4);

    // ---- 6. layer-2 transforms -> bf16 h2 ----
    gemm_mfma<128, false><<<cdiv(NA, 128), 256, 0, stream>>>(res_a, W2a, b2a, h2a_bf, nullptr, nullptr, NA, 256);
    gemm_mfma<128, false><<<cdiv(NP, 128), 256, 0, stream>>>(res_p, W2p, b2p, h2p_bf, nullptr, nullptr, NP, 256);

    // ---- 7. layer-2 (author only: edge types 1 p->a, 3 a->a) ----
    node_scoresN<32, 3><<<cdiv(NA * 4, 256), 256, 0, stream>>>(
        h2a_bf, att2d + 1 * 128, att2s + 3 * 128, att2d + 3 * 128, nullptr,
        sd21, ss23, sd23, nullptr, NA);
    node_scoresN<32, 1><<<cdiv(NP * 4, 256), 256, 0, stream>>>(
        h2p_bf, att2s + 1 * 128, nullptr, nullptr, nullptr,
        ss21, nullptr, nullptr, nullptr, NP);
    edge_logits<<<cdiv(NE, 256), 256, 0, stream>>>(csrc[1], cdst[1], ss21, sd21, alog[1], NE);
    edge_logits<<<cdiv(NE, 256), 256, 0, stream>>>(csrc[3], cdst[3], ss23, sd23, alog[3], NE);
    agg_bf<128><<<cdiv(NA, 4), 256, 0, stream>>>(h2p_bf, alog[1], csrc[1], rp[1], g21, NA);
    agg_bf<128><<<cdiv(NA, 4), 256, 0, stream>>>(h2a_bf, alog[3], csrc[3], rp[3], g23, NA);

    // ---- 8. layer-2 semantic attention -> d_out ----
    gemm_mfma<128, true><<<cdiv(NA, 128), 256, 0, stream>>>(g21, k2W, k2b, nullptr, q2, &sc[4], NA, 128);
    gemm_mfma<128, true><<<cdiv(NA, 128), 256, 0, stream>>>(g23, k2W, k2b, nullptr, q2, &sc[5], NA, 128);
    softmax2<<<1, 1, 0, stream>>>(&sc[4], 1.f / NA, &sc[10]);
    combine2<<<cdiv(NA * D2 / 4, 256), 256, 0, stream>>>(g21, g23, &sc[10], (float*)d_out, NA * D2 / 4);
}

// Round 4
// 484.198 us; speedup vs baseline: 2.6096x; 1.4932x over previous
//
#include <hip/hip_runtime.h>
#include <math.h>

// HAN (2-layer) on MI355X.
// GEMMs via split-bf16 MFMA; bf16 feature gather with 16-lane-group-per-node
// aggregation (4 nodes/wave for MLP); all per-edge-type kernels batched via
// blockIdx.y. Layer-2 computes only author-needed work.

#define NA 20000
#define NP 30000
#define NE 200000
#define D1 256   // HID
#define D2 128   // OUT

typedef __attribute__((ext_vector_type(8))) short short8v;
typedef __attribute__((ext_vector_type(4))) short short4v;
typedef __attribute__((ext_vector_type(4))) float floatx4;
typedef __attribute__((ext_vector_type(8))) unsigned short ushort8v;
typedef __attribute__((ext_vector_type(4))) unsigned short ushort4v;

static __device__ __forceinline__ float lrelu(float x) { return x >= 0.f ? x : 0.2f * x; }

static __device__ __forceinline__ unsigned short bftrunc(float x) {
    return (unsigned short)(__float_as_uint(x) >> 16);
}
static __device__ __forceinline__ float bf2f(unsigned short b) {
    return __uint_as_float(((unsigned)b) << 16);
}
// round-to-nearest-even f32 -> bf16
static __device__ __forceinline__ unsigned short bfrn(float x) {
    unsigned u = __float_as_uint(x);
    return (unsigned short)((u + 0x7FFFu + ((u >> 16) & 1u)) >> 16);
}

static inline int cdiv(int a, int b) { return (a + b - 1) / b; }

// ================= CSR build (4 edge types batched) =================
struct CsrBatch {
    const int* srcv[4];
    const int* dstv[4];
    int* cnt[4];      // degree counts, then cursors
    int* csrc[4];     // CSR-ordered src indices
    int* cdst[4];     // CSR-ordered dst indices
};

__global__ __launch_bounds__(256) void count_deg_b(CsrBatch c, int n) {
    const int ty = blockIdx.y;
    const int i = blockIdx.x * 256 + threadIdx.x;
    if (i < n) atomicAdd(&c.cnt[ty][c.dstv[ty][i]], 1);
}

__global__ __launch_bounds__(256) void fill_csr_b(CsrBatch c, int n) {
    const int ty = blockIdx.y;
    const int i = blockIdx.x * 256 + threadIdx.x;
    if (i < n) {
        const int d = c.dstv[ty][i];
        const int p = atomicAdd(&c.cnt[ty][d], 1);
        c.csrc[ty][p] = c.srcv[ty][i];
        c.cdst[ty][p] = d;
    }
}

// 4 edge-type exclusive scans in one launch (blockIdx = type), wave-shuffle based.
__global__ __launch_bounds__(1024) void exscan4(int* __restrict__ curbase,
                                                int* __restrict__ rpbase) {
    const int off_c[4] = {0, NP, NP + NA, NP + NA + NP};
    const int off_r[4] = {0, NP + 1, NP + NA + 2, NP + NA + NP + 3};
    const int ns[4] = {NP, NA, NP, NA};
    const int b = blockIdx.x;
    int* cur = curbase + off_c[b];
    int* rp = rpbase + off_r[b];
    const int n = ns[b];
    __shared__ int wsum[16];
    __shared__ int carry_s;
    const int t = threadIdx.x, wv = t >> 6, ln = t & 63;
    if (t == 0) carry_s = 0;
    __syncthreads();
    for (int base = 0; base < n; base += 1024) {
        const int i = base + t;
        const int v = (i < n) ? cur[i] : 0;
        int x = v;
#pragma unroll
        for (int off = 1; off < 64; off <<= 1) {
            int y = __shfl_up(x, off);
            if (ln >= off) x += y;
        }
        if (ln == 63) wsum[wv] = x;
        __syncthreads();
        if (wv == 0) {
            int s = (ln < 16) ? wsum[ln] : 0;
#pragma unroll
            for (int off = 1; off < 16; off <<= 1) {
                int y = __shfl_up(s, off);
                if (ln >= off) s += y;
            }
            if (ln < 16) wsum[ln] = s;
        }
        __syncthreads();
        const int woff = (wv == 0) ? 0 : wsum[wv - 1];
        const int c = carry_s;
        const int ex = c + woff + x - v;
        if (i < n) { rp[i] = ex; cur[i] = ex; }
        __syncthreads();
        if (t == 1023) carry_s = c + wsum[15];
        __syncthreads();
    }
    if (t == 0) rp[n] = carry_s;
}

// ================= split-bf16 MFMA GEMM, batched over blockIdx.y =================
// SCORE=false: C[ty] = bf16_rn(A[ty]@W[ty] + bias[ty])
// SCORE=true : atomicAdd(score[ty], sum tanh(acc+bias)*qv)
template <int NT>
struct GemmBatch {
    const float* A[NT];
    const float* W[NT];
    const float* bias[NT];
    unsigned short* C[NT];
    int M[NT];
};

template <int BN, bool SCORE, int NT>
__global__ __launch_bounds__(256) void gemm_b(
    GemmBatch<NT> g, const float* __restrict__ qv, float* __restrict__ score, int K) {
    constexpr int WGN = BN / 64;
    constexpr int WGM = 4 / WGN;
    constexpr int BM = WGM * 64;
    constexpr int LDK = 40;
    constexpr int KPT = BN / 8;
    const int ty = blockIdx.y;
    const int M = g.M[ty];
    const int bm = blockIdx.x * BM;
    if (bm >= M) return;   // uniform per block; no barrier crossed yet
    const float* __restrict__ A = g.A[ty];
    const float* __restrict__ W = g.W[ty];
    const float* __restrict__ bias = g.bias[ty];
    __shared__ unsigned short As[2][BM][LDK];
    __shared__ unsigned short Bs[2][BN][LDK];
    const int t = threadIdx.x;
    const int lane = t & 63, wid = t >> 6;
    const int wr = wid / WGN, wc = wid % WGN;
    const int fq = lane >> 4, fr = lane & 15;
    const int bn_ = t % BN;
    const int kb_ = (t / BN) * KPT;
    floatx4 acc[4][4];
#pragma unroll
    for (int i = 0; i < 4; ++i)
#pragma unroll
        for (int j = 0; j < 4; ++j) acc[i][j] = {0.f, 0.f, 0.f, 0.f};

    for (int kt = 0; kt < K; kt += 32) {
#pragma unroll
        for (int i = 0; i < BM / 32; ++i) {
            const int fi = t + 256 * i;
            const int row = fi >> 3, k4 = (fi & 7) * 4;
            const int gr = bm + row;
            float4 v = {0.f, 0.f, 0.f, 0.f};
            if (gr < M) v = *(const float4*)&A[(size_t)gr * K + kt + k4];
            const float xs4[4] = {v.x, v.y, v.z, v.w};
            short4v hi, lo;
#pragma unroll
            for (int k = 0; k < 4; ++k) {
                const unsigned short hb = bftrunc(xs4[k]);
                hi[k] = (short)hb;
                lo[k] = (short)bftrunc(xs4[k] - bf2f(hb));
            }
            *(short4v*)&As[0][row][k4] = hi;
            *(short4v*)&As[1][row][k4] = lo;
        }
#pragma unroll
        for (int w = 0; w < KPT / 8; ++w) {
            short8v hi, lo;
#pragma unroll
            for (int k = 0; k < 8; ++k) {
                const float x = W[(size_t)(kt + kb_ + w * 8 + k) * BN + bn_];
                const unsigned short hb = bftrunc(x);
                hi[k] = (short)hb;
                lo[k] = (short)bftrunc(x - bf2f(hb));
            }
            *(short8v*)&Bs[0][bn_][kb_ + w * 8] = hi;
            *(short8v*)&Bs[1][bn_][kb_ + w * 8] = lo;
        }
        __syncthreads();
        short8v ah[4], al[4], bh[4], bl[4];
#pragma unroll
        for (int f = 0; f < 4; ++f) {
            const int ar = wr * 64 + f * 16 + fr;
            ah[f] = *(const short8v*)&As[0][ar][fq * 8];
            al[f] = *(const short8v*)&As[1][ar][fq * 8];
            const int bc = wc * 64 + f * 16 + fr;
            bh[f] = *(const short8v*)&Bs[0][bc][fq * 8];
            bl[f] = *(const short8v*)&Bs[1][bc][fq * 8];
        }
#pragma unroll
        for (int i = 0; i < 4; ++i)
#pragma unroll
            for (int j = 0; j < 4; ++j) {
                acc[i][j] = __builtin_amdgcn_mfma_f32_16x16x32_bf16(ah[i], bh[j], acc[i][j], 0, 0, 0);
                acc[i][j] = __builtin_amdgcn_mfma_f32_16x16x32_bf16(ah[i], bl[j], acc[i][j], 0, 0, 0);
                acc[i][j] = __builtin_amdgcn_mfma_f32_16x16x32_bf16(al[i], bh[j], acc[i][j], 0, 0, 0);
            }
        __syncthreads();
    }
    if constexpr (!SCORE) {
        unsigned short* __restrict__ Cb = g.C[ty];
#pragma unroll
        for (int i = 0; i < 4; ++i) {
            const int gr0 = bm + wr * 64 + i * 16 + fq * 4;
#pragma unroll
            for (int j = 0; j < 4; ++j) {
                const int col = wc * 64 + j * 16 + fr;
                const float b = bias[col];
#pragma unroll
                for (int r = 0; r < 4; ++r) {
                    const int gr = gr0 + r;
                    if (gr < M) Cb[(size_t)gr * BN + col] = bfrn(acc[i][j][r] + b);
                }
            }
        }
    } else {
        __shared__ float red[256];
        float partial = 0.f;
#pragma unroll
        for (int i = 0; i < 4; ++i) {
            const int gr0 = bm + wr * 64 + i * 16 + fq * 4;
#pragma unroll
            for (int j = 0; j < 4; ++j) {
                const int col = wc * 64 + j * 16 + fr;
                const float b = bias[col], q = qv[col];
#pragma unroll
                for (int r = 0; r < 4; ++r) {
                    if (gr0 + r < M) partial += tanhf(acc[i][j][r] + b) * q;
                }
            }
        }
        red[t] = partial;
        __syncthreads();
        for (int s = 128; s > 0; s >>= 1) {
            if (t < s) red[t] += red[t + s];
            __syncthreads();
        }
        if (t == 0) atomicAdd(&score[ty], red[0]);
    }
}

// ================ fused node attention-score dots (bf16 h, up to 4 att vectors) ================
template <int HD, int NSC>
__global__ __launch_bounds__(256) void node_scoresN(
    const unsigned short* __restrict__ hx,
    const float* __restrict__ a0, const float* __restrict__ a1,
    const float* __restrict__ a2, const float* __restrict__ a3,
    float* __restrict__ o0, float* __restrict__ o1,
    float* __restrict__ o2, float* __restrict__ o3, int n) {
    const int idx = blockIdx.x * blockDim.x + threadIdx.x;
    const int node = idx >> 2, hh = idx & 3;
    if (node >= n) return;
    const unsigned short* row = hx + (size_t)node * (4 * HD) + hh * HD;
    float s0 = 0.f, s1 = 0.f, s2 = 0.f, s3 = 0.f;
#pragma unroll
    for (int d = 0; d < HD; d += 4) {
        ushort4v xv = *(const ushort4v*)&row[d];
        const float x0 = bf2f(xv[0]), x1 = bf2f(xv[1]), x2 = bf2f(xv[2]), x3 = bf2f(xv[3]);
        float4 v = *(const float4*)&a0[hh * HD + d];
        s0 += x0 * v.x + x1 * v.y + x2 * v.z + x3 * v.w;
        if constexpr (NSC > 1) {
            v = *(const float4*)&a1[hh * HD + d];
            s1 += x0 * v.x + x1 * v.y + x2 * v.z + x3 * v.w;
        }
        if constexpr (NSC > 2) {
            v = *(const float4*)&a2[hh * HD + d];
            s2 += x0 * v.x + x1 * v.y + x2 * v.z + x3 * v.w;
        }
        if constexpr (NSC > 3) {
            v = *(const float4*)&a3[hh * HD + d];
            s3 += x0 * v.x + x1 * v.y + x2 * v.z + x3 * v.w;
        }
    }
    o0[idx] = s0;
    if constexpr (NSC > 1) o1[idx] = s1;
    if constexpr (NSC > 2) o2[idx] = s2;
    if constexpr (NSC > 3) o3[idx] = s3;
}

// ================= per-edge 4-head logits (batched) =================
template <int NT>
struct ElogBatch {
    const int* csrc[NT];
    const int* cdst[NT];
    const float* ss[NT];
    const float* sd[NT];
    float4* alog[NT];
};

template <int NT>
__global__ __launch_bounds__(256) void edge_logits_b(ElogBatch<NT> a, int n) {
    const int ty = blockIdx.y;
    const int i = blockIdx.x * 256 + threadIdx.x;
    if (i >= n) return;
    const int s = a.csrc[ty][i], d = a.cdst[ty][i];
    const float4 av = *(const float4*)&a.ss[ty][s * 4];
    const float4 bv = *(const float4*)&a.sd[ty][d * 4];
    float4 o = {lrelu(av.x + bv.x), lrelu(av.y + bv.y), lrelu(av.z + bv.z), lrelu(av.w + bv.w)};
    a.alog[ty][i] = o;
}

// ========== fused segment softmax + bf16 gather + relu (16-lane group per node) ==========
template <int EPL>
static __device__ __forceinline__ void accum(const unsigned short* p, float ea, float* acc) {
#pragma unroll
    for (int w = 0; w < EPL / 8; ++w) {
        ushort8v x = *(const ushort8v*)(p + w * 8);
#pragma unroll
        for (int k = 0; k < 8; ++k) acc[w * 8 + k] += bf2f(x[k]) * ea;
    }
}

template <int NT>
struct AggBatch {
    const unsigned short* xs[NT];
    const float* alog[NT];   // [E][4] logits
    const int* csrc[NT];
    const int* rowptr[NT];
    float* out[NT];
    int ndst[NT];
};

// 256 threads = 16 groups of 16 lanes; group -> one dst node.
// lane g owns elems [g*EPL, (g+1)*EPL); its head = g>>2 (EPL*4 elems per head).
template <int D, int NT>
__global__ __launch_bounds__(256) void agg_b(AggBatch<NT> a) {
    constexpr int EPL = D / 16;
    const int ty = blockIdx.y;
    const int gid = blockIdx.x * 16 + (threadIdx.x >> 4);
    if (gid >= a.ndst[ty]) return;
    const int g = threadIdx.x & 15;
    const int h = g >> 2, sub = g & 3;
    const int* __restrict__ rp = a.rowptr[ty];
    const int e0 = rp[gid], e1 = rp[gid + 1];
    const float* __restrict__ lg = a.alog[ty];
    const int* __restrict__ cs = a.csrc[ty];
    const unsigned short* __restrict__ xs = a.xs[ty];
    // per-head max: stride-4 scan within the 4-lane head subgroup + 2 shuffles
    float mx = -INFINITY;
    for (int e = e0 + sub; e < e1; e += 4)
        mx = fmaxf(mx, lg[(size_t)e * 4 + h]);
    mx = fmaxf(mx, __shfl_xor(mx, 1));
    mx = fmaxf(mx, __shfl_xor(mx, 2));
    float acc[EPL] = {};
    float denom = 0.f;
    int e = e0;
    for (; e + 2 <= e1; e += 2) {
        const int r0 = cs[e], r1 = cs[e + 1];
        const float l0 = lg[(size_t)e * 4 + h];
        const float l1 = lg[(size_t)(e + 1) * 4 + h];
        const float ea0 = __expf(l0 - mx), ea1 = __expf(l1 - mx);
        denom += ea0 + ea1;
        accum<EPL>(xs + (size_t)r0 * D + g * EPL, ea0, acc);
        accum<EPL>(xs + (size_t)r1 * D + g * EPL, ea1, acc);
    }
    if (e < e1) {
        const int r0 = cs[e];
        const float l0 = lg[(size_t)e * 4 + h];
        const float ea0 = __expf(l0 - mx);
        denom += ea0;
        accum<EPL>(xs + (size_t)r0 * D + g * EPL, ea0, acc);
    }
    const float inv = 1.f / (denom + 1e-16f);
    float* __restrict__ orow = a.out[ty] + (size_t)gid * D + g * EPL;
#pragma unroll
    for (int w = 0; w < EPL / 4; ++w) {
        float4 o = {fmaxf(acc[w * 4 + 0] * inv, 0.f), fmaxf(acc[w * 4 + 1] * inv, 0.f),
                    fmaxf(acc[w * 4 + 2] * inv, 0.f), fmaxf(acc[w * 4 + 3] * inv, 0.f)};
        *(float4*)&orow[w * 4] = o;
    }
}

// ================= semantic softmax folded into combine =================
struct CombBatch {
    const float* a[2];
    const float* b[2];
    float* o[2];
    int n4[2];
    int slot[2];
    float invN[2];
};

__global__ __launch_bounds__(256) void combine_b(CombBatch c, const float* __restrict__ sc) {
    const int ty = blockIdx.y;
    const int i = blockIdx.x * 256 + threadIdx.x;
    if (i >= c.n4[ty]) return;
    const float s0 = sc[c.slot[ty]] * c.invN[ty];
    const float s1 = sc[c.slot[ty] + 1] * c.invN[ty];
    const float m = fmaxf(s0, s1);
    const float e0 = expf(s0 - m), e1 = expf(s1 - m);
    const float w0 = e0 / (e0 + e1), w1 = e1 / (e0 + e1);
    float4 x = ((const float4*)c.a[ty])[i], y = ((const float4*)c.b[ty])[i];
    float4 o = {w0 * x.x + w1 * y.x, w0 * x.y + w1 * y.y,
                w0 * x.z + w1 * y.z, w0 * x.w + w1 * y.w};
    ((float4*)c.o[ty])[i] = o;
}

extern "C" void kernel_launch(void* const* d_in, const int* in_sizes, int n_in,
                              void* d_out, int out_size, void* d_ws, size_t ws_size,
                              hipStream_t stream) {
    const float* x_a = (const float*)d_in[0];
    const float* x_p = (const float*)d_in[1];
    const int* src[4] = {(const int*)d_in[2], (const int*)d_in[4], (const int*)d_in[6], (const int*)d_in[8]};
    const int* dst[4] = {(const int*)d_in[3], (const int*)d_in[5], (const int*)d_in[7], (const int*)d_in[9]};
    const float* W1a = (const float*)d_in[10]; const float* b1a = (const float*)d_in[11];
    const float* W1p = (const float*)d_in[12]; const float* b1p = (const float*)d_in[13];
    const float* att1s = (const float*)d_in[14]; const float* att1d = (const float*)d_in[15];
    const float* q1 = (const float*)d_in[16];
    const float* k1W = (const float*)d_in[17]; const float* k1b = (const float*)d_in[18];
    const float* W2a = (const float*)d_in[19]; const float* b2a = (const float*)d_in[20];
    const float* W2p = (const float*)d_in[21]; const float* b2p = (const float*)d_in[22];
    const float* att2s = (const float*)d_in[23]; const float* att2d = (const float*)d_in[24];
    const float* q2 = (const float*)d_in[25];
    const float* k2W = (const float*)d_in[26]; const float* k2b = (const float*)d_in[27];

    // ---- workspace layout ----
    char* wp = (char*)d_ws;
    unsigned short* h1a_bf = (unsigned short*)wp; wp += (size_t)NA * D1 * 2;
    unsigned short* h1p_bf = (unsigned short*)wp; wp += (size_t)NP * D1 * 2;
    float* agg0 = (float*)wp; wp += (size_t)NP * D1 * 4;
    float* agg1 = (float*)wp; wp += (size_t)NA * D1 * 4;
    float* agg2 = (float*)wp; wp += (size_t)NP * D1 * 4;
    float* agg3 = (float*)wp; wp += (size_t)NA * D1 * 4;
    float* sv = (float*)wp; wp += (size_t)(16 * NA + 16 * NP) * 4;
    float4* alogb = (float4*)wp; wp += (size_t)4 * NE * 16;
    float* sc = (float*)wp; wp += 16 * 4;
    int* rp_base = (int*)wp; wp += (size_t)(NP + NA + NP + NA + 4) * 4;
    int* cur_base = (int*)wp; wp += (size_t)(NP + NA + NP + NA) * 4;
    int* csrc_base = (int*)wp; wp += (size_t)4 * NE * 4;
    int* cdst_base = (int*)wp; wp += (size_t)4 * NE * 4;
    const size_t need_bytes = (size_t)(wp - (char*)d_ws);
    if (ws_size < need_bytes) return;

    int* rp[4] = {rp_base, rp_base + NP + 1, rp_base + NP + NA + 2, rp_base + NP + NA + NP + 3};
    int* cur[4] = {cur_base, cur_base + NP, cur_base + NP + NA, cur_base + NP + NA + NP};
    int* csrc[4]; int* cdst[4]; float4* alog[4];
    for (int i = 0; i < 4; ++i) {
        csrc[i] = csrc_base + (size_t)i * NE;
        cdst[i] = cdst_base + (size_t)i * NE;
        alog[i] = alogb + (size_t)i * NE;
    }
    // L1 score arrays
    float* ss0 = sv;             float* sd0 = ss0 + NA * 4;
    float* ss1 = sd0 + NP * 4;   float* sd1 = ss1 + NP * 4;
    float* ss2 = sd1 + NA * 4;   float* sd2 = ss2 + NP * 4;
    float* ss3 = sd2 + NP * 4;   float* sd3 = ss3 + NA * 4;
    // region reuse
    float* res_p = agg0;  // combine in-place
    float* res_a = agg1;
    unsigned short* h2a_bf = (unsigned short*)agg2;
    unsigned short* h2p_bf = h2a_bf + (size_t)NA * D2;
    float* g21 = agg3;
    float* g23 = agg3 + (size_t)NA * D2;
    float* ss21 = sv;             float* sd21 = ss21 + NP * 4;
    float* ss23 = sd21 + NA * 4;  float* sd23 = ss23 + NA * 4;

    // ---- 0. zero counters ----
    hipMemsetAsync(cur_base, 0, (size_t)(NP + NA + NP + NA) * sizeof(int), stream);
    hipMemsetAsync(sc, 0, 16 * sizeof(float), stream);

    // ---- 1. CSR build (one launch per phase, 4 types via blockIdx.y) ----
    CsrBatch cb;
    for (int i = 0; i < 4; ++i) {
        cb.srcv[i] = src[i]; cb.dstv[i] = dst[i];
        cb.cnt[i] = cur[i]; cb.csrc[i] = csrc[i]; cb.cdst[i] = cdst[i];
    }
    count_deg_b<<<dim3(cdiv(NE, 256), 4), 256, 0, stream>>>(cb, NE);
    exscan4<<<4, 1024, 0, stream>>>(cur_base, rp_base);
    fill_csr_b<<<dim3(cdiv(NE, 256), 4), 256, 0, stream>>>(cb, NE);

    // ---- 2. layer-1 transforms -> bf16 h (batched) ----
    GemmBatch<2> t1 = {{x_a, x_p}, {W1a, W1p}, {b1a, b1p}, {h1a_bf, h1p_bf}, {NA, NP}};
    gemm_b<256, false, 2><<<dim3(cdiv(NP, 64), 2), 256, 0, stream>>>(t1, nullptr, nullptr, 256);

    // ---- 3. fused node attention scalars (layer 1) ----
    node_scoresN<64, 4><<<cdiv(NA * 4, 256), 256, 0, stream>>>(
        h1a_bf, att1s + 0 * 256, att1d + 1 * 256, att1s + 3 * 256, att1d + 3 * 256,
        ss0, sd1, ss3, sd3, NA);
    node_scoresN<64, 4><<<cdiv(NP * 4, 256), 256, 0, stream>>>(
        h1p_bf, att1d + 0 * 256, att1s + 1 * 256, att1s + 2 * 256, att1d + 2 * 256,
        sd0, ss1, ss2, sd2, NP);

    // ---- 4. per-edge logits + fused aggregation (batched) ----
    ElogBatch<4> el1 = {{csrc[0], csrc[1], csrc[2], csrc[3]},
                        {cdst[0], cdst[1], cdst[2], cdst[3]},
                        {ss0, ss1, ss2, ss3}, {sd0, sd1, sd2, sd3},
                        {alog[0], alog[1], alog[2], alog[3]}};
    edge_logits_b<4><<<dim3(cdiv(NE, 256), 4), 256, 0, stream>>>(el1, NE);
    AggBatch<4> ab1 = {{h1a_bf, h1p_bf, h1p_bf, h1a_bf},
                       {(const float*)alog[0], (const float*)alog[1], (const float*)alog[2], (const float*)alog[3]},
                       {csrc[0], csrc[1], csrc[2], csrc[3]},
                       {rp[0], rp[1], rp[2], rp[3]},
                       {agg0, agg1, agg2, agg3},
                       {NP, NA, NP, NA}};
    agg_b<256, 4><<<dim3(cdiv(NP, 16), 4), 256, 0, stream>>>(ab1);

    // ---- 5. semantic scores (layer 1, batched) + combine (softmax folded) ----
    GemmBatch<4> s1 = {{agg0, agg2, agg1, agg3}, {k1W, k1W, k1W, k1W},
                       {k1b, k1b, k1b, k1b},
                       {nullptr, nullptr, nullptr, nullptr},
                       {NP, NP, NA, NA}};
    gemm_b<256, true, 4><<<dim3(cdiv(NP, 64), 4), 256, 0, stream>>>(s1, q1, sc, 256);
    CombBatch c1 = {{agg0, agg1}, {agg2, agg3}, {res_p, res_a},
                    {NP * (D1 / 4), NA * (D1 / 4)}, {0, 2}, {1.f / NP, 1.f / NA}};
    combine_b<<<dim3(cdiv(NP * (D1 / 4), 256), 2), 256, 0, stream>>>(c1, sc);

    // ---- 6. layer-2 transforms -> bf16 h2 (batched) ----
    GemmBatch<2> t2 = {{res_a, res_p}, {W2a, W2p}, {b2a, b2p}, {h2a_bf, h2p_bf}, {NA, NP}};
    gemm_b<128, false, 2><<<dim3(cdiv(NP, 128), 2), 256, 0, stream>>>(t2, nullptr, nullptr, 256);

    // ---- 7. layer-2 (author only: edge types 1 p->a, 3 a->a) ----
    node_scoresN<32, 3><<<cdiv(NA * 4, 256), 256, 0, stream>>>(
        h2a_bf, att2d + 1 * 128, att2s + 3 * 128, att2d + 3 * 128, nullptr,
        sd21, ss23, sd23, nullptr, NA);
    node_scoresN<32, 1><<<cdiv(NP * 4, 256), 256, 0, stream>>>(
        h2p_bf, att2s + 1 * 128, nullptr, nullptr, nullptr,
        ss21, nullptr, nullptr, nullptr, NP);
    ElogBatch<2> el2 = {{csrc[1], csrc[3]}, {cdst[1], cdst[3]},
                        {ss21, ss23}, {sd21, sd23}, {alog[1], alog[3]}};
    edge_logits_b<2><<<dim3(cdiv(NE, 256), 2), 256, 0, stream>>>(el2, NE);
    AggBatch<2> ab2 = {{h2p_bf, h2a_bf},
                       {(const float*)alog[1], (const float*)alog[3]},
                       {csrc[1], csrc[3]}, {rp[1], rp[3]},
                       {g21, g23}, {NA, NA}};
    agg_b<128, 2><<<dim3(cdiv(NA, 16), 2), 256, 0, stream>>>(ab2);

    // ---- 8. layer-2 semantic attention -> d_out ----
    GemmBatch<2> s2 = {{g21, g23}, {k2W, k2W}, {k2b, k2b}, {nullptr, nullptr}, {NA, NA}};
    gemm_b<128, true, 2><<<dim3(cdiv(NA, 128), 2), 256, 0, stream>>>(s2, q2, sc + 4, 128);
    CombBatch c2 = {{g21, g21}, {g23, g23}, {(float*)d_out, (float*)d_out},
                    {NA * (D2 / 4), NA * (D2 / 4)}, {4, 4}, {1.f / NA, 1.f / NA}};
    combine_b<<<dim3(cdiv(NA * (D2 / 4), 256), 1), 256, 0, stream>>>(c2, sc);
}

// Round 5
// 470.185 us; speedup vs baseline: 2.6874x; 1.0298x over previous
//
#include <hip/hip_runtime.h>
#include <math.h>

// HAN (2-layer) on MI355X.
// GEMMs via split-bf16 MFMA with precomputed split-W images staged by
// global_load_lds; bf16 feature gather with 16-lane-group-per-node
// aggregation; all per-edge-type kernels batched via blockIdx.y.
// Layer-2 computes only author-needed work.

#define NA 20000
#define NP 30000
#define NE 200000
#define D1 256   // HID
#define D2 128   // OUT
#define LDK 40   // padded LDS k-stride (ushorts): 80 B rows, 16B-aligned slots

typedef __attribute__((ext_vector_type(8))) short short8v;
typedef __attribute__((ext_vector_type(4))) float floatx4;
typedef __attribute__((ext_vector_type(8))) unsigned short ushort8v;
typedef __attribute__((ext_vector_type(4))) unsigned short ushort4v;

static __device__ __forceinline__ float lrelu(float x) { return x >= 0.f ? x : 0.2f * x; }

static __device__ __forceinline__ unsigned short bftrunc(float x) {
    return (unsigned short)(__float_as_uint(x) >> 16);
}
static __device__ __forceinline__ float bf2f(unsigned short b) {
    return __uint_as_float(((unsigned)b) << 16);
}
// round-to-nearest-even f32 -> bf16
static __device__ __forceinline__ unsigned short bfrn(float x) {
    unsigned u = __float_as_uint(x);
    return (unsigned short)((u + 0x7FFFu + ((u >> 16) & 1u)) >> 16);
}

typedef __attribute__((address_space(1))) const unsigned int as1_uint;
typedef __attribute__((address_space(3))) unsigned int as3_uint;
static __device__ __forceinline__ void gl_lds16(const void* g, void* l) {
    __builtin_amdgcn_global_load_lds((as1_uint*)g, (as3_uint*)l, 16, 0, 0);
}

static inline int cdiv(int a, int b) { return (a + b - 1) / b; }

// ================= CSR build (4 edge types batched) =================
struct CsrBatch {
    const int* srcv[4];
    const int* dstv[4];
    int* cnt[4];
    int* csrc[4];
    int* cdst[4];
};

__global__ __launch_bounds__(256) void count_deg_b(CsrBatch c, int n) {
    const int ty = blockIdx.y;
    const int i = blockIdx.x * 256 + threadIdx.x;
    if (i < n) atomicAdd(&c.cnt[ty][c.dstv[ty][i]], 1);
}

__global__ __launch_bounds__(256) void fill_csr_b(CsrBatch c, int n) {
    const int ty = blockIdx.y;
    const int i = blockIdx.x * 256 + threadIdx.x;
    if (i < n) {
        const int d = c.dstv[ty][i];
        const int p = atomicAdd(&c.cnt[ty][d], 1);
        c.csrc[ty][p] = c.srcv[ty][i];
        c.cdst[ty][p] = d;
    }
}

// 4 edge-type exclusive scans in one launch (blockIdx = type), wave-shuffle based.
__global__ __launch_bounds__(1024) void exscan4(int* __restrict__ curbase,
                                                int* __restrict__ rpbase) {
    const int off_c[4] = {0, NP, NP + NA, NP + NA + NP};
    const int off_r[4] = {0, NP + 1, NP + NA + 2, NP + NA + NP + 3};
    const int ns[4] = {NP, NA, NP, NA};
    const int b = blockIdx.x;
    int* cur = curbase + off_c[b];
    int* rp = rpbase + off_r[b];
    const int n = ns[b];
    __shared__ int wsum[16];
    __shared__ int carry_s;
    const int t = threadIdx.x, wv = t >> 6, ln = t & 63;
    if (t == 0) carry_s = 0;
    __syncthreads();
    for (int base = 0; base < n; base += 1024) {
        const int i = base + t;
        const int v = (i < n) ? cur[i] : 0;
        int x = v;
#pragma unroll
        for (int off = 1; off < 64; off <<= 1) {
            int y = __shfl_up(x, off);
            if (ln >= off) x += y;
        }
        if (ln == 63) wsum[wv] = x;
        __syncthreads();
        if (wv == 0) {
            int s = (ln < 16) ? wsum[ln] : 0;
#pragma unroll
            for (int off = 1; off < 16; off <<= 1) {
                int y = __shfl_up(s, off);
                if (ln >= off) s += y;
            }
            if (ln < 16) wsum[ln] = s;
        }
        __syncthreads();
        const int woff = (wv == 0) ? 0 : wsum[wv - 1];
        const int c = carry_s;
        const int ex = c + woff + x - v;
        if (i < n) { rp[i] = ex; cur[i] = ex; }
        __syncthreads();
        if (t == 1023) carry_s = c + wsum[15];
        __syncthreads();
    }
    if (t == 0) rp[n] = carry_s;
}

// ================= W -> split-bf16 LDS-image prep (6 matrices batched) =================
// Image layout (ushort): img[kt][part][col][LDK], k-tile = 32. Slot 4 (pad) = 0.
struct PrepBatch {
    const float* W[6];
    unsigned short* img[6];
    int N[6];
    int nsl[6];   // (K/32)*2*5*N slots of 8 ushorts
};

__global__ __launch_bounds__(256) void w_prep(PrepBatch p) {
    const int m = blockIdx.y;
    const int idx = blockIdx.x * 256 + threadIdx.x;
    if (idx >= p.nsl[m]) return;
    const int N = p.N[m];
    const int col = idx % N;
    int rest = idx / N;
    const int slot = rest % 5; rest /= 5;
    const int part = rest & 1;
    const int kt = rest >> 1;
    unsigned short* dst = p.img[m] + ((size_t)(kt * 2 + part) * N + col) * LDK + slot * 8;
    short8v o;
    if (slot == 4) {
#pragma unroll
        for (int k = 0; k < 8; ++k) o[k] = 0;
    } else {
        const float* wsrc = p.W[m] + (size_t)(kt * 32 + slot * 8) * N + col;
#pragma unroll
        for (int k = 0; k < 8; ++k) {
            const float x = wsrc[(size_t)k * N];
            const unsigned short hb = bftrunc(x);
            o[k] = part ? (short)bftrunc(x - bf2f(hb)) : (short)hb;
        }
    }
    *(short8v*)dst = o;
}

// ================= split-bf16 MFMA GEMM, batched over blockIdx.y =================
// SCORE=false: C[ty] = bf16_rn(A[ty]@W[ty] + bias[ty])
// SCORE=true : atomicAdd(score[ty], sum tanh(acc+bias)*qv)
template <int NT>
struct GemmBatch {
    const float* A[NT];
    const unsigned short* Wimg[NT];   // prepped split-W image
    const float* bias[NT];
    unsigned short* C[NT];
    int M[NT];
};

template <int BN, bool SCORE, int NT>
__global__ __launch_bounds__(256) void gemm_b(
    GemmBatch<NT> g, const float* __restrict__ qv, float* __restrict__ score, int K) {
    constexpr int WGN = BN / 64;      // waves along N
    constexpr int WGM = 4 / WGN;      // waves along M
    constexpr int BM = WGM * 64;
    constexpr int NCH = (2 * BN * LDK * 2) / 1024;   // 1KB gload chunks per k-tile
    const int ty = blockIdx.y;
    const int M = g.M[ty];
    const int bm = blockIdx.x * BM;
    if (bm >= M) return;
    const float* __restrict__ A = g.A[ty];
    const unsigned short* __restrict__ Wimg = g.Wimg[ty];
    const float* __restrict__ bias = g.bias[ty];
    __shared__ __attribute__((aligned(16))) unsigned short As[2][BM][LDK];
    __shared__ __attribute__((aligned(16))) unsigned short Bs[2][BN][LDK];
    const int t = threadIdx.x;
    const int lane = t & 63, wid = t >> 6;
    const int wr = wid / WGN, wc = wid % WGN;
    const int fq = lane >> 4, fr = lane & 15;
    floatx4 acc[4][4];
#pragma unroll
    for (int i = 0; i < 4; ++i)
#pragma unroll
        for (int j = 0; j < 4; ++j) acc[i][j] = {0.f, 0.f, 0.f, 0.f};

    for (int kt = 0; kt < K; kt += 32) {
        // ---- stage B: direct global->LDS copy of the prepped image ----
        const char* wsrc = (const char*)(Wimg + (size_t)(kt >> 5) * (2 * BN * LDK));
        char* ldsb = (char*)&Bs[0][0][0];
#pragma unroll
        for (int i = 0; i < NCH / 4; ++i) {
            const int chunk = (wid * (NCH / 4) + i) * 1024;
            gl_lds16(wsrc + chunk + lane * 16, ldsb + chunk);
        }
        // ---- stage A tile (BM x 32 f32), split hi/lo, 16B slot writes ----
#pragma unroll
        for (int i = t; i < BM * 4; i += 256) {
            const int row = i >> 2, slot = i & 3;
            const int gr = bm + row;
            float4 v0 = {0.f, 0.f, 0.f, 0.f}, v1 = {0.f, 0.f, 0.f, 0.f};
            if (gr < M) {
                const float* ap = &A[(size_t)gr * K + kt + slot * 8];
                v0 = *(const float4*)ap;
                v1 = *(const float4*)(ap + 4);
            }
            const float xs8[8] = {v0.x, v0.y, v0.z, v0.w, v1.x, v1.y, v1.z, v1.w};
            short8v hi, lo;
#pragma unroll
            for (int k = 0; k < 8; ++k) {
                const unsigned short hb = bftrunc(xs8[k]);
                hi[k] = (short)hb;
                lo[k] = (short)bftrunc(xs8[k] - bf2f(hb));
            }
            *(short8v*)&As[0][row][slot * 8] = hi;
            *(short8v*)&As[1][row][slot * 8] = lo;
        }
        __syncthreads();
        // ---- fragments + MFMA ----
        short8v ah[4], al[4], bh[4], bl[4];
#pragma unroll
        for (int f = 0; f < 4; ++f) {
            const int ar = wr * 64 + f * 16 + fr;
            ah[f] = *(const short8v*)&As[0][ar][fq * 8];
            al[f] = *(const short8v*)&As[1][ar][fq * 8];
            const int bc = wc * 64 + f * 16 + fr;
            bh[f] = *(const short8v*)&Bs[0][bc][fq * 8];
            bl[f] = *(const short8v*)&Bs[1][bc][fq * 8];
        }
#pragma unroll
        for (int i = 0; i < 4; ++i)
#pragma unroll
            for (int j = 0; j < 4; ++j) {
                acc[i][j] = __builtin_amdgcn_mfma_f32_16x16x32_bf16(ah[i], bh[j], acc[i][j], 0, 0, 0);
                acc[i][j] = __builtin_amdgcn_mfma_f32_16x16x32_bf16(ah[i], bl[j], acc[i][j], 0, 0, 0);
                acc[i][j] = __builtin_amdgcn_mfma_f32_16x16x32_bf16(al[i], bh[j], acc[i][j], 0, 0, 0);
            }
        __syncthreads();
    }
    if constexpr (!SCORE) {
        unsigned short* __restrict__ Cb = g.C[ty];
#pragma unroll
        for (int i = 0; i < 4; ++i) {
            const int gr0 = bm + wr * 64 + i * 16 + fq * 4;
#pragma unroll
            for (int j = 0; j < 4; ++j) {
                const int col = wc * 64 + j * 16 + fr;
                const float b = bias[col];
#pragma unroll
                for (int r = 0; r < 4; ++r) {
                    const int gr = gr0 + r;
                    if (gr < M) Cb[(size_t)gr * BN + col] = bfrn(acc[i][j][r] + b);
                }
            }
        }
    } else {
        __shared__ float red[256];
        float partial = 0.f;
#pragma unroll
        for (int i = 0; i < 4; ++i) {
            const int gr0 = bm + wr * 64 + i * 16 + fq * 4;
#pragma unroll
            for (int j = 0; j < 4; ++j) {
                const int col = wc * 64 + j * 16 + fr;
                const float b = bias[col], q = qv[col];
#pragma unroll
                for (int r = 0; r < 4; ++r) {
                    if (gr0 + r < M) partial += tanhf(acc[i][j][r] + b) * q;
                }
            }
        }
        red[t] = partial;
        __syncthreads();
        for (int s = 128; s > 0; s >>= 1) {
            if (t < s) red[t] += red[t + s];
            __syncthreads();
        }
        if (t == 0) atomicAdd(&score[ty], red[0]);
    }
}

// ================ fused node attention-score dots (bf16 h, up to 4 att vectors) ================
template <int HD, int NSC>
__global__ __launch_bounds__(256) void node_scoresN(
    const unsigned short* __restrict__ hx,
    const float* __restrict__ a0, const float* __restrict__ a1,
    const float* __restrict__ a2, const float* __restrict__ a3,
    float* __restrict__ o0, float* __restrict__ o1,
    float* __restrict__ o2, float* __restrict__ o3, int n) {
    const int idx = blockIdx.x * blockDim.x + threadIdx.x;
    const int node = idx >> 2, hh = idx & 3;
    if (node >= n) return;
    const unsigned short* row = hx + (size_t)node * (4 * HD) + hh * HD;
    float s0 = 0.f, s1 = 0.f, s2 = 0.f, s3 = 0.f;
#pragma unroll
    for (int d = 0; d < HD; d += 4) {
        ushort4v xv = *(const ushort4v*)&row[d];
        const float x0 = bf2f(xv[0]), x1 = bf2f(xv[1]), x2 = bf2f(xv[2]), x3 = bf2f(xv[3]);
        float4 v = *(const float4*)&a0[hh * HD + d];
        s0 += x0 * v.x + x1 * v.y + x2 * v.z + x3 * v.w;
        if constexpr (NSC > 1) {
            v = *(const float4*)&a1[hh * HD + d];
            s1 += x0 * v.x + x1 * v.y + x2 * v.z + x3 * v.w;
        }
        if constexpr (NSC > 2) {
            v = *(const float4*)&a2[hh * HD + d];
            s2 += x0 * v.x + x1 * v.y + x2 * v.z + x3 * v.w;
        }
        if constexpr (NSC > 3) {
            v = *(const float4*)&a3[hh * HD + d];
            s3 += x0 * v.x + x1 * v.y + x2 * v.z + x3 * v.w;
        }
    }
    o0[idx] = s0;
    if constexpr (NSC > 1) o1[idx] = s1;
    if constexpr (NSC > 2) o2[idx] = s2;
    if constexpr (NSC > 3) o3[idx] = s3;
}

// ================= per-edge 4-head logits (batched) =================
template <int NT>
struct ElogBatch {
    const int* csrc[NT];
    const int* cdst[NT];
    const float* ss[NT];
    const float* sd[NT];
    float4* alog[NT];
};

template <int NT>
__global__ __launch_bounds__(256) void edge_logits_b(ElogBatch<NT> a, int n) {
    const int ty = blockIdx.y;
    const int i = blockIdx.x * 256 + threadIdx.x;
    if (i >= n) return;
    const int s = a.csrc[ty][i], d = a.cdst[ty][i];
    const float4 av = *(const float4*)&a.ss[ty][s * 4];
    const float4 bv = *(const float4*)&a.sd[ty][d * 4];
    float4 o = {lrelu(av.x + bv.x), lrelu(av.y + bv.y), lrelu(av.z + bv.z), lrelu(av.w + bv.w)};
    a.alog[ty][i] = o;
}

// ========== fused segment softmax + bf16 gather + relu (16-lane group per node) ==========
template <int EPL>
static __device__ __forceinline__ void accum(const unsigned short* p, float ea, float* acc) {
#pragma unroll
    for (int w = 0; w < EPL / 8; ++w) {
        ushort8v x = *(const ushort8v*)(p + w * 8);
#pragma unroll
        for (int k = 0; k < 8; ++k) acc[w * 8 + k] += bf2f(x[k]) * ea;
    }
}

template <int NT>
struct AggBatch {
    const unsigned short* xs[NT];
    const float* alog[NT];
    const int* csrc[NT];
    const int* rowptr[NT];
    float* out[NT];
    int ndst[NT];
};

template <int D, int NT>
__global__ __launch_bounds__(256) void agg_b(AggBatch<NT> a) {
    constexpr int EPL = D / 16;
    const int ty = blockIdx.y;
    const int gid = blockIdx.x * 16 + (threadIdx.x >> 4);
    if (gid >= a.ndst[ty]) return;
    const int g = threadIdx.x & 15;
    const int h = g >> 2, sub = g & 3;
    const int* __restrict__ rp = a.rowptr[ty];
    const int e0 = rp[gid], e1 = rp[gid + 1];
    const float* __restrict__ lg = a.alog[ty];
    const int* __restrict__ cs = a.csrc[ty];
    const unsigned short* __restrict__ xs = a.xs[ty];
    float mx = -INFINITY;
    for (int e = e0 + sub; e < e1; e += 4)
        mx = fmaxf(mx, lg[(size_t)e * 4 + h]);
    mx = fmaxf(mx, __shfl_xor(mx, 1));
    mx = fmaxf(mx, __shfl_xor(mx, 2));
    float acc[EPL] = {};
    float denom = 0.f;
    int e = e0;
    for (; e + 2 <= e1; e += 2) {
        const int r0 = cs[e], r1 = cs[e + 1];
        const float l0 = lg[(size_t)e * 4 + h];
        const float l1 = lg[(size_t)(e + 1) * 4 + h];
        const float ea0 = __expf(l0 - mx), ea1 = __expf(l1 - mx);
        denom += ea0 + ea1;
        accum<EPL>(xs + (size_t)r0 * D + g * EPL, ea0, acc);
        accum<EPL>(xs + (size_t)r1 * D + g * EPL, ea1, acc);
    }
    if (e < e1) {
        const int r0 = cs[e];
        const float l0 = lg[(size_t)e * 4 + h];
        const float ea0 = __expf(l0 - mx);
        denom += ea0;
        accum<EPL>(xs + (size_t)r0 * D + g * EPL, ea0, acc);
    }
    const float inv = 1.f / (denom + 1e-16f);
    float* __restrict__ orow = a.out[ty] + (size_t)gid * D + g * EPL;
#pragma unroll
    for (int w = 0; w < EPL / 4; ++w) {
        float4 o = {fmaxf(acc[w * 4 + 0] * inv, 0.f), fmaxf(acc[w * 4 + 1] * inv, 0.f),
                    fmaxf(acc[w * 4 + 2] * inv, 0.f), fmaxf(acc[w * 4 + 3] * inv, 0.f)};
        *(float4*)&orow[w * 4] = o;
    }
}

// ================= semantic softmax folded into combine =================
struct CombBatch {
    const float* a[2];
    const float* b[2];
    float* o[2];
    int n4[2];
    int slot[2];
    float invN[2];
};

__global__ __launch_bounds__(256) void combine_b(CombBatch c, const float* __restrict__ sc) {
    const int ty = blockIdx.y;
    const int i = blockIdx.x * 256 + threadIdx.x;
    if (i >= c.n4[ty]) return;
    const float s0 = sc[c.slot[ty]] * c.invN[ty];
    const float s1 = sc[c.slot[ty] + 1] * c.invN[ty];
    const float m = fmaxf(s0, s1);
    const float e0 = expf(s0 - m), e1 = expf(s1 - m);
    const float w0 = e0 / (e0 + e1), w1 = e1 / (e0 + e1);
    float4 x = ((const float4*)c.a[ty])[i], y = ((const float4*)c.b[ty])[i];
    float4 o = {w0 * x.x + w1 * y.x, w0 * x.y + w1 * y.y,
                w0 * x.z + w1 * y.z, w0 * x.w + w1 * y.w};
    ((float4*)c.o[ty])[i] = o;
}

extern "C" void kernel_launch(void* const* d_in, const int* in_sizes, int n_in,
                              void* d_out, int out_size, void* d_ws, size_t ws_size,
                              hipStream_t stream) {
    const float* x_a = (const float*)d_in[0];
    const float* x_p = (const float*)d_in[1];
    const int* src[4] = {(const int*)d_in[2], (const int*)d_in[4], (const int*)d_in[6], (const int*)d_in[8]};
    const int* dst[4] = {(const int*)d_in[3], (const int*)d_in[5], (const int*)d_in[7], (const int*)d_in[9]};
    const float* W1a = (const float*)d_in[10]; const float* b1a = (const float*)d_in[11];
    const float* W1p = (const float*)d_in[12]; const float* b1p = (const float*)d_in[13];
    const float* att1s = (const float*)d_in[14]; const float* att1d = (const float*)d_in[15];
    const float* q1 = (const float*)d_in[16];
    const float* k1W = (const float*)d_in[17]; const float* k1b = (const float*)d_in[18];
    const float* W2a = (const float*)d_in[19]; const float* b2a = (const float*)d_in[20];
    const float* W2p = (const float*)d_in[21]; const float* b2p = (const float*)d_in[22];
    const float* att2s = (const float*)d_in[23]; const float* att2d = (const float*)d_in[24];
    const float* q2 = (const float*)d_in[25];
    const float* k2W = (const float*)d_in[26]; const float* k2b = (const float*)d_in[27];

    // ---- workspace layout ----
    char* wp = (char*)d_ws;
    unsigned short* h1a_bf = (unsigned short*)wp; wp += (size_t)NA * D1 * 2;
    unsigned short* h1p_bf = (unsigned short*)wp; wp += (size_t)NP * D1 * 2;
    float* agg0 = (float*)wp; wp += (size_t)NP * D1 * 4;
    float* agg1 = (float*)wp; wp += (size_t)NA * D1 * 4;
    float* agg2 = (float*)wp; wp += (size_t)NP * D1 * 4;
    float* agg3 = (float*)wp; wp += (size_t)NA * D1 * 4;
    float* sv = (float*)wp; wp += (size_t)(16 * NA + 16 * NP) * 4;
    float4* alogb = (float4*)wp; wp += (size_t)4 * NE * 16;
    float* sc = (float*)wp; wp += 16 * 4;
    int* rp_base = (int*)wp; wp += (size_t)(NP + NA + NP + NA + 4) * 4;
    int* cur_base = (int*)wp; wp += (size_t)(NP + NA + NP + NA) * 4;
    int* csrc_base = (int*)wp; wp += (size_t)4 * NE * 4;
    int* cdst_base = (int*)wp; wp += (size_t)4 * NE * 4;
    // split-W images (ushort): [K/32][2][N][LDK]
    unsigned short* img_w1a = (unsigned short*)wp; wp += (size_t)8 * 2 * 256 * LDK * 2;
    unsigned short* img_w1p = (unsigned short*)wp; wp += (size_t)8 * 2 * 256 * LDK * 2;
    unsigned short* img_k1w = (unsigned short*)wp; wp += (size_t)8 * 2 * 256 * LDK * 2;
    unsigned short* img_w2a = (unsigned short*)wp; wp += (size_t)8 * 2 * 128 * LDK * 2;
    unsigned short* img_w2p = (unsigned short*)wp; wp += (size_t)8 * 2 * 128 * LDK * 2;
    unsigned short* img_k2w = (unsigned short*)wp; wp += (size_t)4 * 2 * 128 * LDK * 2;
    const size_t need_bytes = (size_t)(wp - (char*)d_ws);
    if (ws_size < need_bytes) return;

    int* rp[4] = {rp_base, rp_base + NP + 1, rp_base + NP + NA + 2, rp_base + NP + NA + NP + 3};
    int* cur[4] = {cur_base, cur_base + NP, cur_base + NP + NA, cur_base + NP + NA + NP};
    int* csrc[4]; int* cdst[4]; float4* alog[4];
    for (int i = 0; i < 4; ++i) {
        csrc[i] = csrc_base + (size_t)i * NE;
        cdst[i] = cdst_base + (size_t)i * NE;
        alog[i] = alogb + (size_t)i * NE;
    }
    float* ss0 = sv;             float* sd0 = ss0 + NA * 4;
    float* ss1 = sd0 + NP * 4;   float* sd1 = ss1 + NP * 4;
    float* ss2 = sd1 + NA * 4;   float* sd2 = ss2 + NP * 4;
    float* ss3 = sd2 + NP * 4;   float* sd3 = ss3 + NA * 4;
    float* res_p = agg0;
    float* res_a = agg1;
    unsigned short* h2a_bf = (unsigned short*)agg2;
    unsigned short* h2p_bf = h2a_bf + (size_t)NA * D2;
    float* g21 = agg3;
    float* g23 = agg3 + (size_t)NA * D2;
    float* ss21 = sv;             float* sd21 = ss21 + NP * 4;
    float* ss23 = sd21 + NA * 4;  float* sd23 = ss23 + NA * 4;

    // ---- 0. zero counters + W prep ----
    hipMemsetAsync(cur_base, 0, (size_t)(NP + NA + NP + NA) * sizeof(int), stream);
    hipMemsetAsync(sc, 0, 16 * sizeof(float), stream);
    PrepBatch pb = {{W1a, W1p, k1W, W2a, W2p, k2W},
                    {img_w1a, img_w1p, img_k1w, img_w2a, img_w2p, img_k2w},
                    {256, 256, 256, 128, 128, 128},
                    {8 * 2 * 5 * 256, 8 * 2 * 5 * 256, 8 * 2 * 5 * 256,
                     8 * 2 * 5 * 128, 8 * 2 * 5 * 128, 4 * 2 * 5 * 128}};
    w_prep<<<dim3(cdiv(8 * 2 * 5 * 256, 256), 6), 256, 0, stream>>>(pb);

    // ---- 1. CSR build ----
    CsrBatch cb;
    for (int i = 0; i < 4; ++i) {
        cb.srcv[i] = src[i]; cb.dstv[i] = dst[i];
        cb.cnt[i] = cur[i]; cb.csrc[i] = csrc[i]; cb.cdst[i] = cdst[i];
    }
    count_deg_b<<<dim3(cdiv(NE, 256), 4), 256, 0, stream>>>(cb, NE);
    exscan4<<<4, 1024, 0, stream>>>(cur_base, rp_base);
    fill_csr_b<<<dim3(cdiv(NE, 256), 4), 256, 0, stream>>>(cb, NE);

    // ---- 2. layer-1 transforms -> bf16 h (batched) ----
    GemmBatch<2> t1 = {{x_a, x_p}, {img_w1a, img_w1p}, {b1a, b1p}, {h1a_bf, h1p_bf}, {NA, NP}};
    gemm_b<256, false, 2><<<dim3(cdiv(NP, 64), 2), 256, 0, stream>>>(t1, nullptr, nullptr, 256);

    // ---- 3. fused node attention scalars (layer 1) ----
    node_scoresN<64, 4><<<cdiv(NA * 4, 256), 256, 0, stream>>>(
        h1a_bf, att1s + 0 * 256, att1d + 1 * 256, att1s + 3 * 256, att1d + 3 * 256,
        ss0, sd1, ss3, sd3, NA);
    node_scoresN<64, 4><<<cdiv(NP * 4, 256), 256, 0, stream>>>(
        h1p_bf, att1d + 0 * 256, att1s + 1 * 256, att1s + 2 * 256, att1d + 2 * 256,
        sd0, ss1, ss2, sd2, NP);

    // ---- 4. per-edge logits + fused aggregation (batched) ----
    ElogBatch<4> el1 = {{csrc[0], csrc[1], csrc[2], csrc[3]},
                        {cdst[0], cdst[1], cdst[2], cdst[3]},
                        {ss0, ss1, ss2, ss3}, {sd0, sd1, sd2, sd3},
                        {alog[0], alog[1], alog[2], alog[3]}};
    edge_logits_b<4><<<dim3(cdiv(NE, 256), 4), 256, 0, stream>>>(el1, NE);
    AggBatch<4> ab1 = {{h1a_bf, h1p_bf, h1p_bf, h1a_bf},
                       {(const float*)alog[0], (const float*)alog[1], (const float*)alog[2], (const float*)alog[3]},
                       {csrc[0], csrc[1], csrc[2], csrc[3]},
                       {rp[0], rp[1], rp[2], rp[3]},
                       {agg0, agg1, agg2, agg3},
                       {NP, NA, NP, NA}};
    agg_b<256, 4><<<dim3(cdiv(NP, 16), 4), 256, 0, stream>>>(ab1);

    // ---- 5. semantic scores (layer 1, batched) + combine (softmax folded) ----
    GemmBatch<4> s1 = {{agg0, agg2, agg1, agg3}, {img_k1w, img_k1w, img_k1w, img_k1w},
                       {k1b, k1b, k1b, k1b},
                       {nullptr, nullptr, nullptr, nullptr},
                       {NP, NP, NA, NA}};
    gemm_b<256, true, 4><<<dim3(cdiv(NP, 64), 4), 256, 0, stream>>>(s1, q1, sc, 256);
    CombBatch c1 = {{agg0, agg1}, {agg2, agg3}, {res_p, res_a},
                    {NP * (D1 / 4), NA * (D1 / 4)}, {0, 2}, {1.f / NP, 1.f / NA}};
    combine_b<<<dim3(cdiv(NP * (D1 / 4), 256), 2), 256, 0, stream>>>(c1, sc);

    // ---- 6. layer-2 transforms -> bf16 h2 (batched) ----
    GemmBatch<2> t2 = {{res_a, res_p}, {img_w2a, img_w2p}, {b2a, b2p}, {h2a_bf, h2p_bf}, {NA, NP}};
    gemm_b<128, false, 2><<<dim3(cdiv(NP, 128), 2), 256, 0, stream>>>(t2, nullptr, nullptr, 256);

    // ---- 7. layer-2 (author only: edge types 1 p->a, 3 a->a) ----
    node_scoresN<32, 3><<<cdiv(NA * 4, 256), 256, 0, stream>>>(
        h2a_bf, att2d + 1 * 128, att2s + 3 * 128, att2d + 3 * 128, nullptr,
        sd21, ss23, sd23, nullptr, NA);
    node_scoresN<32, 1><<<cdiv(NP * 4, 256), 256, 0, stream>>>(
        h2p_bf, att2s + 1 * 128, nullptr, nullptr, nullptr,
        ss21, nullptr, nullptr, nullptr, NP);
    ElogBatch<2> el2 = {{csrc[1], csrc[3]}, {cdst[1], cdst[3]},
                        {ss21, ss23}, {sd21, sd23}, {alog[1], alog[3]}};
    edge_logits_b<2><<<dim3(cdiv(NE, 256), 2), 256, 0, stream>>>(el2, NE);
    AggBatch<2> ab2 = {{h2p_bf, h2a_bf},
                       {(const float*)alog[1], (const float*)alog[3]},
                       {csrc[1], csrc[3]}, {rp[1], rp[3]},
                       {g21, g23}, {NA, NA}};
    agg_b<128, 2><<<dim3(cdiv(NA, 16), 2), 256, 0, stream>>>(ab2);

    // ---- 8. layer-2 semantic attention -> d_out ----
    GemmBatch<2> s2 = {{g21, g23}, {img_k2w, img_k2w}, {k2b, k2b}, {nullptr, nullptr}, {NA, NA}};
    gemm_b<128, true, 2><<<dim3(cdiv(NA, 128), 2), 256, 0, stream>>>(s2, q2, sc + 4, 128);
    CombBatch c2 = {{g21, g21}, {g23, g23}, {(float*)d_out, (float*)d_out},
                    {NA * (D2 / 4), NA * (D2 / 4)}, {4, 4}, {1.f / NA, 1.f / NA}};
    combine_b<<<dim3(cdiv(NA * (D2 / 4), 256), 1), 256, 0, stream>>>(c2, sc);
}